// Round 12
// baseline (1995.023 us; speedup 1.0000x reference)
//
#include <hip/hip_runtime.h>
#include <hip/hip_bf16.h>

#define BB 4
#define LL 4096
#define EE 1024
#define HH 16
#define II 4096
#define MM (BB*LL)

using f32x4 = __attribute__((ext_vector_type(4))) float;
using s16x8 = __attribute__((ext_vector_type(8))) short;
using u32x4 = __attribute__((ext_vector_type(4))) unsigned int;

__device__ __forceinline__ unsigned short f2bf(float f) {
  union { float f; unsigned u; } x; x.f = f;
  unsigned r = x.u + 0x7fffu + ((x.u >> 16) & 1u);
  return (unsigned short)(r >> 16);
}
__device__ __forceinline__ float bf2f(unsigned short s) {
  union { unsigned u; float f; } x; x.u = ((unsigned)s) << 16;
  return x.f;
}
__device__ __forceinline__ float silu_f(float x) { return x / (1.0f + expf(-x)); }

__device__ __forceinline__ void gll16(const void* g, void* l) {
  __builtin_amdgcn_global_load_lds(
      (const __attribute__((address_space(1))) unsigned int*)g,
      (__attribute__((address_space(3))) unsigned int*)l, 16, 0, 0);
}

// ---------------- adaLN modulation: mod = c @ Wada^T + bada ----------------
__global__ __launch_bounds__(256) void k_mod(const float* __restrict__ c,
    const float* __restrict__ Wada, const float* __restrict__ bada,
    float* __restrict__ mod) {
  __shared__ float cs[EE];
  int b = blockIdx.y;
  int n = blockIdx.x * 256 + threadIdx.x;
  for (int i = threadIdx.x; i < EE; i += 256) cs[i] = c[b*EE + i];
  __syncthreads();
  const float4* wp = (const float4*)(Wada + (size_t)n * EE);
  float acc = 0.f;
  for (int k = 0; k < EE/4; k++) {
    float4 t = wp[k];
    acc += t.x*cs[4*k] + t.y*cs[4*k+1] + t.z*cs[4*k+2] + t.w*cs[4*k+3];
  }
  mod[(size_t)b*6*EE + n] = acc + bada[n];
}

// ------------- coef: c1[b,k]=w[k]*(1+sc), c0[b,k]=sh, for both norms --------
__global__ __launch_bounds__(256) void k_coef(const float* __restrict__ mod,
    const float* __restrict__ w1, const float* __restrict__ w2,
    float* __restrict__ cf1, float* __restrict__ cf2) {
  int k = blockIdx.x * 256 + threadIdx.x;
  int b = blockIdx.y;
  const float* mb = mod + (size_t)b*6*EE;
  cf1[(size_t)b*2048 + k]        = w1[k] * (1.0f + mb[EE + k]);
  cf1[(size_t)b*2048 + 1024 + k] = mb[k];
  cf2[(size_t)b*2048 + k]        = w2[k] * (1.0f + mb[4*EE + k]);
  cf2[(size_t)b*2048 + 1024 + k] = mb[3*EE + k];
}

// ------------- rsig[row] = 1/sqrt(mean(x^2)+eps) ----------------
__global__ __launch_bounds__(256) void k_rsig(const float* __restrict__ in,
    float* __restrict__ rsig) {
  int row = blockIdx.x;
  int t = threadIdx.x;
  float4 v = ((const float4*)(in + (size_t)row * EE))[t];
  float ss = v.x*v.x + v.y*v.y + v.z*v.z + v.w*v.w;
  #pragma unroll
  for (int o = 32; o > 0; o >>= 1) ss += __shfl_down(ss, o, 64);
  __shared__ float red[4];
  if ((t & 63) == 0) red[t >> 6] = ss;
  __syncthreads();
  float tot = red[0] + red[1] + red[2] + red[3];
  if (t == 0) rsig[row] = 1.0f / sqrtf(tot * (1.0f/1024.0f) + 1e-6f);
}

// ---------------- f32 -> bf16 weight conversion ----------------
__global__ __launch_bounds__(256) void k_f2b(const float* __restrict__ s,
    unsigned short* __restrict__ d, int n4) {
  int i = blockIdx.x * 256 + threadIdx.x;
  if (i >= n4) return;
  float4 v = ((const float4*)s)[i];
  ushort4 u; u.x = f2bf(v.x); u.y = f2bf(v.y); u.z = f2bf(v.z); u.w = f2bf(v.w);
  ((ushort4*)d)[i] = u;
}

// ------------- x1 = modulate(rmsnorm(h)) -> split bf16 hi/lo ----------------
__global__ __launch_bounds__(256) void k_split1(const float* __restrict__ h,
    const float* __restrict__ rsig, const float* __restrict__ cf,
    unsigned short* __restrict__ xh, unsigned short* __restrict__ xl) {
  int row = blockIdx.x;
  int t = threadIdx.x;
  int b = row >> 12;
  float rs = rsig[row];
  const float* cfb = cf + (size_t)b*2048;
  float4 v  = ((const float4*)(h + (size_t)row*EE))[t];
  float4 c1 = ((const float4*)cfb)[t];
  float4 c0 = ((const float4*)(cfb + 1024))[t];
  float x0 = fmaf(v.x*rs, c1.x, c0.x);
  float x1 = fmaf(v.y*rs, c1.y, c0.y);
  float x2 = fmaf(v.z*rs, c1.z, c0.z);
  float x3 = fmaf(v.w*rs, c1.w, c0.w);
  ushort4 uh, ul;
  uh.x = f2bf(x0); ul.x = f2bf(x0 - bf2f(uh.x));
  uh.y = f2bf(x1); ul.y = f2bf(x1 - bf2f(uh.y));
  uh.z = f2bf(x2); ul.z = f2bf(x2 - bf2f(uh.z));
  uh.w = f2bf(x3); ul.w = f2bf(x3 - bf2f(uh.w));
  ((ushort4*)(xh + (size_t)row*EE))[t] = uh;
  ((ushort4*)(xl + (size_t)row*EE))[t] = ul;
}

// ------------- x2 = modulate(rmsnorm(h2)) -> bf16 ----------------
__global__ __launch_bounds__(256) void k_split2(const float* __restrict__ in,
    const float* __restrict__ rsig, const float* __restrict__ cf,
    unsigned short* __restrict__ xb) {
  int row = blockIdx.x;
  int t = threadIdx.x;
  int b = row >> 12;
  float rs = rsig[row];
  const float* cfb = cf + (size_t)b*2048;
  float4 v  = ((const float4*)(in + (size_t)row*EE))[t];
  float4 c1 = ((const float4*)cfb)[t];
  float4 c0 = ((const float4*)(cfb + 1024))[t];
  ushort4 u;
  u.x = f2bf(fmaf(v.x*rs, c1.x, c0.x));
  u.y = f2bf(fmaf(v.y*rs, c1.y, c0.y));
  u.z = f2bf(fmaf(v.z*rs, c1.z, c0.z));
  u.w = f2bf(fmaf(v.w*rs, c1.w, c0.w));
  ((ushort4*)(xb + (size_t)row*EE))[t] = u;
}

// ------- K projection: f32 SGEMM 128x128 tile, 8x8/thread (rounds 2/6/8/9
// proven, replay-deterministic). x1 on the fly. Epilogue: silu+RoPE.
__global__ __launch_bounds__(256) void k_sgemmK(
    const float* __restrict__ Ah, const float* __restrict__ W,
    const float* __restrict__ rsig, const float* __restrict__ cf,
    const float* __restrict__ cosT, const float* __restrict__ sinT,
    float* __restrict__ outq) {
  __shared__ float As[8][128];
  __shared__ float Bs[8][128];
  __shared__ float c1s[1024];
  __shared__ float c0s[1024];
  int t = threadIdx.x;
  int tx = t & 15, ty = t >> 4;
  int bm = blockIdx.x, bn = blockIdx.y;
  int srow = t >> 1, sk = (t & 1) * 4;
  int bidx = bm >> 5;
  for (int i = t; i < 1024; i += 256) {
    c1s[i] = cf[(size_t)bidx*2048 + i];
    c0s[i] = cf[(size_t)bidx*2048 + 1024 + i];
  }
  int arow = bm*128 + srow;
  float rsA = rsig[arow];
  const float* ap = Ah + (size_t)arow*EE + sk;
  const float* bp = W + (size_t)(bn*128 + srow)*EE + sk;
  float acc[8][8];
  #pragma unroll
  for (int i = 0; i < 8; i++)
    #pragma unroll
    for (int j = 0; j < 8; j++) acc[i][j] = 0.f;
  float4 pa = *(const float4*)ap;
  float4 pb = *(const float4*)bp;
  int c0 = (tx < 8) ? tx*4 : 64 + (tx - 8)*4;
  __syncthreads();
  for (int k0 = 0; k0 < EE; k0 += 8) {
    int kb = k0 + sk;
    As[sk+0][srow] = fmaf(pa.x*rsA, c1s[kb+0], c0s[kb+0]);
    As[sk+1][srow] = fmaf(pa.y*rsA, c1s[kb+1], c0s[kb+1]);
    As[sk+2][srow] = fmaf(pa.z*rsA, c1s[kb+2], c0s[kb+2]);
    As[sk+3][srow] = fmaf(pa.w*rsA, c1s[kb+3], c0s[kb+3]);
    Bs[sk+0][srow] = pb.x; Bs[sk+1][srow] = pb.y; Bs[sk+2][srow] = pb.z; Bs[sk+3][srow] = pb.w;
    __syncthreads();
    if (k0 + 8 < EE) {
      pa = *(const float4*)(ap + k0 + 8);
      pb = *(const float4*)(bp + k0 + 8);
    }
    #pragma unroll
    for (int k = 0; k < 8; k++) {
      float4 a0 = *(const float4*)&As[k][ty*8];
      float4 a1 = *(const float4*)&As[k][ty*8+4];
      float4 b0 = *(const float4*)&Bs[k][c0];
      float4 b1 = *(const float4*)&Bs[k][c0+32];
      float av[8] = {a0.x,a0.y,a0.z,a0.w,a1.x,a1.y,a1.z,a1.w};
      float bv[8]  = {b0.x,b0.y,b0.z,b0.w,b1.x,b1.y,b1.z,b1.w};
      #pragma unroll
      for (int i = 0; i < 8; i++)
        #pragma unroll
        for (int j = 0; j < 8; j++)
          acc[i][j] = fmaf(av[i], bv[j], acc[i][j]);
    }
    __syncthreads();
  }
  int head = bn*2 + (tx >= 8 ? 1 : 0);
  int d0 = (tx < 8) ? tx*4 : (tx - 8)*4;
  #pragma unroll
  for (int i = 0; i < 8; i++) {
    int m = bm*128 + ty*8 + i;
    int b = m >> 12, l = m & 4095;
    const float* cp = cosT + (size_t)l*64;
    const float* sp = sinT + (size_t)l*64;
    float4 cl  = *(const float4*)(cp + d0);
    float4 slv = *(const float4*)(sp + d0);
    float4 chv = *(const float4*)(cp + d0 + 32);
    float4 shv = *(const float4*)(sp + d0 + 32);
    float sA0 = silu_f(acc[i][0]), sA1 = silu_f(acc[i][1]), sA2 = silu_f(acc[i][2]), sA3 = silu_f(acc[i][3]);
    float sB0 = silu_f(acc[i][4]), sB1 = silu_f(acc[i][5]), sB2 = silu_f(acc[i][6]), sB3 = silu_f(acc[i][7]);
    float q00 = sA0*cl.x - sB0*slv.x;
    float q01 = sA1*cl.y - sB1*slv.y;
    float q02 = sA2*cl.z - sB2*slv.z;
    float q03 = sA3*cl.w - sB3*slv.w;
    float q10 = sB0*chv.x + sA0*shv.x;
    float q11 = sB1*chv.y + sA1*shv.y;
    float q12 = sB2*chv.z + sA2*shv.z;
    float q13 = sB3*chv.w + sA3*shv.w;
    float* op = outq + ((size_t)(b*HH + head)*LL + l)*64;
    *(float4*)(op + d0)      = make_float4(q00, q01, q02, q03);
    *(float4*)(op + d0 + 32) = make_float4(q10, q11, q12, q13);
  }
}

// ------- Q projection: 3-term split-bf16 MFMA GEMM (frozen since r6) --------
__global__ __launch_bounds__(256) void k_qk(
    const unsigned short* __restrict__ xh, const unsigned short* __restrict__ xl,
    const float* __restrict__ W,
    const float* __restrict__ cosT, const float* __restrict__ sinT,
    float* __restrict__ outq) {
  __shared__ unsigned short Ah[128*32];
  __shared__ unsigned short Al[128*32];
  __shared__ unsigned short Bh[64*40];
  __shared__ unsigned short Bl[64*40];
  int t = threadIdx.x, w = t >> 6, lane = t & 63;
  int bm = blockIdx.x, bn = blockIdx.y;
  int wm = (w & 1) * 64;
  int wn = (w >> 1) * 16;
  int r16 = lane & 15, kg = lane >> 4;
  int rin = lane >> 2, slot = lane & 3;
  int ar0 = w*32 + rin, ar1 = ar0 + 16;
  const unsigned short* ahg0 = xh + (size_t)(bm*128 + ar0)*EE + (size_t)((((ar0>>1)&3) ^ slot) * 8);
  const unsigned short* ahg1 = xh + (size_t)(bm*128 + ar1)*EE + (size_t)((((ar1>>1)&3) ^ slot) * 8);
  const unsigned short* alg0 = xl + (size_t)(bm*128 + ar0)*EE + (size_t)((((ar0>>1)&3) ^ slot) * 8);
  const unsigned short* alg1 = xl + (size_t)(bm*128 + ar1)*EE + (size_t)((((ar1>>1)&3) ^ slot) * 8);
  unsigned short* ahl0 = &Ah[(w*32 + 0) * 32];
  unsigned short* ahl1 = &Ah[(w*32 + 16) * 32];
  unsigned short* all0 = &Al[(w*32 + 0) * 32];
  unsigned short* all1 = &Al[(w*32 + 16) * 32];
  int srow = t >> 2, koff = (t & 3) * 8;
  const float* bp = W + (size_t)(bn*64 + srow)*EE + koff;
  float4 pb0 = *(const float4*)(bp + 0);
  float4 pb1 = *(const float4*)(bp + 4);
  f32x4 acc[4][2];
  #pragma unroll
  for (int i = 0; i < 4; i++) { acc[i][0] = (f32x4){0,0,0,0}; acc[i][1] = (f32x4){0,0,0,0}; }

  for (int k0 = 0; k0 < EE; k0 += 32) {
    gll16(ahg0 + k0, ahl0);
    gll16(ahg1 + k0, ahl1);
    gll16(alg0 + k0, all0);
    gll16(alg1 + k0, all1);
    {
      unsigned short h0 = f2bf(pb0.x), h1 = f2bf(pb0.y), h2 = f2bf(pb0.z), h3 = f2bf(pb0.w);
      unsigned short h4 = f2bf(pb1.x), h5 = f2bf(pb1.y), h6 = f2bf(pb1.z), h7 = f2bf(pb1.w);
      unsigned short l0 = f2bf(pb0.x - bf2f(h0)), l1 = f2bf(pb0.y - bf2f(h1));
      unsigned short l2 = f2bf(pb0.z - bf2f(h2)), l3 = f2bf(pb0.w - bf2f(h3));
      unsigned short l4 = f2bf(pb1.x - bf2f(h4)), l5 = f2bf(pb1.y - bf2f(h5));
      unsigned short l6 = f2bf(pb1.z - bf2f(h6)), l7 = f2bf(pb1.w - bf2f(h7));
      u32x4 uh, ul;
      uh[0] = ((unsigned)h1<<16)|h0; uh[1] = ((unsigned)h3<<16)|h2;
      uh[2] = ((unsigned)h5<<16)|h4; uh[3] = ((unsigned)h7<<16)|h6;
      ul[0] = ((unsigned)l1<<16)|l0; ul[1] = ((unsigned)l3<<16)|l2;
      ul[2] = ((unsigned)l5<<16)|l4; ul[3] = ((unsigned)l7<<16)|l6;
      *(u32x4*)&Bh[srow*40 + koff] = uh;
      *(u32x4*)&Bl[srow*40 + koff] = ul;
    }
    __syncthreads();
    if (k0 + 32 < EE) {
      pb0 = *(const float4*)(bp + k0 + 32);
      pb1 = *(const float4*)(bp + k0 + 36);
    }
    int brow0 = wn + r16, brow1 = wn + 32 + r16;
    s16x8 bh0 = *(const s16x8*)&Bh[brow0*40 + kg*8];
    s16x8 bl0 = *(const s16x8*)&Bl[brow0*40 + kg*8];
    s16x8 bh1 = *(const s16x8*)&Bh[brow1*40 + kg*8];
    s16x8 bl1 = *(const s16x8*)&Bl[brow1*40 + kg*8];
    #pragma unroll
    for (int i = 0; i < 4; i++) {
      int row = wm + i*16 + r16;
      int sw = ((((row>>1)&3) ^ kg) << 3);
      s16x8 ah = *(const s16x8*)&Ah[row*32 + sw];
      s16x8 al = *(const s16x8*)&Al[row*32 + sw];
      acc[i][0] = __builtin_amdgcn_mfma_f32_16x16x32_bf16(ah, bh0, acc[i][0], 0, 0, 0);
      acc[i][0] = __builtin_amdgcn_mfma_f32_16x16x32_bf16(ah, bl0, acc[i][0], 0, 0, 0);
      acc[i][0] = __builtin_amdgcn_mfma_f32_16x16x32_bf16(al, bh0, acc[i][0], 0, 0, 0);
      acc[i][1] = __builtin_amdgcn_mfma_f32_16x16x32_bf16(ah, bh1, acc[i][1], 0, 0, 0);
      acc[i][1] = __builtin_amdgcn_mfma_f32_16x16x32_bf16(ah, bl1, acc[i][1], 0, 0, 0);
      acc[i][1] = __builtin_amdgcn_mfma_f32_16x16x32_bf16(al, bh1, acc[i][1], 0, 0, 0);
    }
    __syncthreads();
  }
  int d = wn + r16;
  #pragma unroll
  for (int i = 0; i < 4; i++) {
    #pragma unroll
    for (int r = 0; r < 4; r++) {
      int mm = bm*128 + wm + i*16 + kg*4 + r;
      int b = mm >> 12, l = mm & 4095;
      const float* cp = cosT + (size_t)l*64;
      const float* sp = sinT + (size_t)l*64;
      float sl = silu_f(acc[i][0][r]);
      float sh = silu_f(acc[i][1][r]);
      float qlo = sl*cp[d]      - sh*sp[d];
      float qhi = sh*cp[d + 32] + sl*sp[d + 32];
      float* op = outq + (((size_t)(b*HH + bn))*LL + l)*64;
      op[d]      = qlo;
      op[d + 32] = qhi;
    }
  }
}

// ---- bf16 MFMA GEMM, pure global_load_lds both sides, 128x128 tile.
// EPI: 0=V(bf16 (B,H,L,64)) 1=WO(out=res+g1*acc) 4=D(out=res+g2*acc, in-place)
template<int EPI, int KLEN, int SA, int SB>
__global__ __launch_bounds__(256) void k_gemm2(
    const unsigned short* __restrict__ Ab,
    const unsigned short* __restrict__ Bw,
    int kbB, int bnoff,
    const float* __restrict__ res, const float* __restrict__ mod,
    unsigned short* __restrict__ outb, float* __restrict__ outf) {
  __shared__ unsigned short As[128 * 32];
  __shared__ unsigned short Bs[128 * 32];
  int t = threadIdx.x, w = t >> 6, lane = t & 63;
  int bm = blockIdx.x, bn = blockIdx.y;
  int wm = (w >> 1) * 64, wn = (w & 1) * 64;
  int rin = lane >> 2, slot = lane & 3;
  int brow0 = w*32 + rin, brow1 = brow0 + 16;
  int swz0 = (((brow0>>1)&3) ^ slot) * 8;
  int swz1 = (((brow1>>1)&3) ^ slot) * 8;
  const unsigned short* ag0 = Ab + (size_t)(bm*128 + brow0)*SA + swz0;
  const unsigned short* ag1 = Ab + (size_t)(bm*128 + brow1)*SA + swz1;
  const unsigned short* bg0 = Bw + (size_t)(bnoff + bn*128 + brow0)*SB + kbB + swz0;
  const unsigned short* bg1 = Bw + (size_t)(bnoff + bn*128 + brow1)*SB + kbB + swz1;
  unsigned short* al0 = &As[(w*32 + 0) * 32];
  unsigned short* al1 = &As[(w*32 + 16) * 32];
  unsigned short* bl0 = &Bs[(w*32 + 0) * 32];
  unsigned short* bl1 = &Bs[(w*32 + 16) * 32];
  f32x4 acc[4][4];
  #pragma unroll
  for (int i = 0; i < 4; i++)
    #pragma unroll
    for (int j = 0; j < 4; j++) acc[i][j] = (f32x4){0.f, 0.f, 0.f, 0.f};
  int r16 = lane & 15, kg = lane >> 4;
  for (int k0 = 0; k0 < KLEN; k0 += 32) {
    gll16(ag0 + k0, al0);
    gll16(ag1 + k0, al1);
    gll16(bg0 + k0, bl0);
    gll16(bg1 + k0, bl1);
    __syncthreads();
    s16x8 af[4], bfr[4];
    #pragma unroll
    for (int i = 0; i < 4; i++) {
      int row = wm + i*16 + r16;
      af[i] = *(const s16x8*)&As[row*32 + ((((row>>1)&3) ^ kg) << 3)];
    }
    #pragma unroll
    for (int j = 0; j < 4; j++) {
      int row = wn + j*16 + r16;
      bfr[j] = *(const s16x8*)&Bs[row*32 + ((((row>>1)&3) ^ kg) << 3)];
    }
    #pragma unroll
    for (int i = 0; i < 4; i++)
      #pragma unroll
      for (int j = 0; j < 4; j++)
        acc[i][j] = __builtin_amdgcn_mfma_f32_16x16x32_bf16(af[i], bfr[j], acc[i][j], 0, 0, 0);
    __syncthreads();
  }
  #pragma unroll
  for (int i = 0; i < 4; i++) {
    #pragma unroll
    for (int j = 0; j < 4; j++) {
      int nn = bn*128 + wn + j*16 + r16;
      #pragma unroll
      for (int r = 0; r < 4; r++) {
        int mm = bm*128 + wm + i*16 + kg*4 + r;
        float v = acc[i][j][r];
        if constexpr (EPI == 0) {
          int b = mm >> 12, l = mm & 4095, hh = nn >> 6, dd = nn & 63;
          outb[(((size_t)(b*HH + hh))*LL + l)*64 + dd] = f2bf(v);
        } else if constexpr (EPI == 1) {
          int b = mm >> 12;
          size_t o = (size_t)mm*EE + nn;
          outf[o] = res[o] + mod[(size_t)b*6*EE + 2*EE + nn] * v;
        } else {
          int b = mm >> 12;
          size_t o = (size_t)mm*EE + nn;
          outf[o] = res[o] + mod[(size_t)b*6*EE + 5*EE + nn] * v;
        }
      }
    }
  }
}

// ---- fused G+U: P = bf16(silu(x2@Wg^T)*(x2@Wu^T)), pure gload_lds staging ---
__global__ __launch_bounds__(256) void k_gemmGU(
    const unsigned short* __restrict__ Ab,
    const unsigned short* __restrict__ Wg, const unsigned short* __restrict__ Wu,
    int bnoff, unsigned short* __restrict__ outP) {
  __shared__ unsigned short As[128 * 32];
  __shared__ unsigned short Bg[128 * 32];
  __shared__ unsigned short Bu[128 * 32];
  int t = threadIdx.x, w = t >> 6, lane = t & 63;
  int bm = blockIdx.x, bn = blockIdx.y;
  int wm = (w >> 1) * 64, wn = (w & 1) * 64;
  int rin = lane >> 2, slot = lane & 3;
  int brow0 = w*32 + rin, brow1 = brow0 + 16;
  int swz0 = (((brow0>>1)&3) ^ slot) * 8;
  int swz1 = (((brow1>>1)&3) ^ slot) * 8;
  const unsigned short* ag0 = Ab + (size_t)(bm*128 + brow0)*EE + swz0;
  const unsigned short* ag1 = Ab + (size_t)(bm*128 + brow1)*EE + swz1;
  size_t boff0 = (size_t)(bnoff + bn*128 + brow0)*EE + swz0;
  size_t boff1 = (size_t)(bnoff + bn*128 + brow1)*EE + swz1;
  const unsigned short* bg0 = Wg + boff0;
  const unsigned short* bg1 = Wg + boff1;
  const unsigned short* bu0 = Wu + boff0;
  const unsigned short* bu1 = Wu + boff1;
  unsigned short* al0  = &As[(w*32 + 0) * 32];
  unsigned short* al1  = &As[(w*32 + 16) * 32];
  unsigned short* blg0 = &Bg[(w*32 + 0) * 32];
  unsigned short* blg1 = &Bg[(w*32 + 16) * 32];
  unsigned short* blu0 = &Bu[(w*32 + 0) * 32];
  unsigned short* blu1 = &Bu[(w*32 + 16) * 32];
  f32x4 accg[4][4], accu[4][4];
  #pragma unroll
  for (int i = 0; i < 4; i++)
    #pragma unroll
    for (int j = 0; j < 4; j++) {
      accg[i][j] = (f32x4){0.f, 0.f, 0.f, 0.f};
      accu[i][j] = (f32x4){0.f, 0.f, 0.f, 0.f};
    }
  int r16 = lane & 15, kg = lane >> 4;
  for (int k0 = 0; k0 < EE; k0 += 32) {
    gll16(ag0 + k0, al0);
    gll16(ag1 + k0, al1);
    gll16(bg0 + k0, blg0);
    gll16(bg1 + k0, blg1);
    gll16(bu0 + k0, blu0);
    gll16(bu1 + k0, blu1);
    __syncthreads();
    s16x8 af[4], bgf[4], buf[4];
    #pragma unroll
    for (int i = 0; i < 4; i++) {
      int row = wm + i*16 + r16;
      af[i] = *(const s16x8*)&As[row*32 + ((((row>>1)&3) ^ kg) << 3)];
    }
    #pragma unroll
    for (int j = 0; j < 4; j++) {
      int row = wn + j*16 + r16;
      int sw = row*32 + ((((row>>1)&3) ^ kg) << 3);
      bgf[j] = *(const s16x8*)&Bg[sw];
      buf[j] = *(const s16x8*)&Bu[sw];
    }
    #pragma unroll
    for (int i = 0; i < 4; i++)
      #pragma unroll
      for (int j = 0; j < 4; j++) {
        accg[i][j] = __builtin_amdgcn_mfma_f32_16x16x32_bf16(af[i], bgf[j], accg[i][j], 0, 0, 0);
        accu[i][j] = __builtin_amdgcn_mfma_f32_16x16x32_bf16(af[i], buf[j], accu[i][j], 0, 0, 0);
      }
    __syncthreads();
  }
  #pragma unroll
  for (int i = 0; i < 4; i++) {
    #pragma unroll
    for (int j = 0; j < 4; j++) {
      int nn = bn*128 + wn + j*16 + r16;
      #pragma unroll
      for (int r = 0; r < 4; r++) {
        int mm = bm*128 + wm + i*16 + kg*4 + r;
        outP[(size_t)mm*2048 + nn] = f2bf(silu_f(accg[i][j][r]) * accu[i][j][r]);
      }
    }
  }
}

// ---- kv partials over 512-l chunks ----
__global__ __launch_bounds__(256) void k_kvpart(const float* __restrict__ kr,
    const unsigned short* __restrict__ vtb, float* __restrict__ kvp) {
  int bi = blockIdx.x;
  int bh = bi >> 3, ch = bi & 7;
  const float* kp = kr + ((size_t)bh*LL + ch*512)*64;
  const unsigned short* vp = vtb + ((size_t)bh*LL + ch*512)*64;
  __shared__ float k8[8][64];
  __shared__ float v8[8][64];
  __shared__ float sw8[8], cw8[8];
  int t = threadIdx.x;
  int d = t >> 2, mq = (t & 3) * 16;
  float accS[16], accC[16];
  #pragma unroll
  for (int q = 0; q < 16; q++) { accS[q] = 0.f; accC[q] = 0.f; }
  float ksS = 0.f, ksC = 0.f;
  for (int l0 = 0; l0 < 512; l0 += 8) {
    __syncthreads();
    #pragma unroll
    for (int rep = 0; rep < 2; rep++) {
      int idx = rep*256 + t;
      k8[idx>>6][idx&63] = kp[(size_t)(l0 + (idx>>6))*64 + (idx&63)];
      v8[idx>>6][idx&63] = bf2f(vp[(size_t)(l0 + (idx>>6))*64 + (idx&63)]);
    }
    if (t < 8) {
      int gl = ch*512 + l0 + t;
      float idxv = 1.5707964f * (float)(gl + 1) * (1.0f/4096.0f);
      sw8[t] = sinf(idxv);
      cw8[t] = cosf(idxv);
    }
    __syncthreads();
    #pragma unroll
    for (int l = 0; l < 8; l++) {
      float kd = k8[l][d];
      float s = kd * sw8[l];
      float c = kd * cw8[l];
      ksS += s; ksC += c;
      const float4* vv = (const float4*)&v8[l][mq];
      #pragma unroll
      for (int q = 0; q < 4; q++) {
        float4 x = vv[q];
        accS[4*q+0] = fmaf(s, x.x, accS[4*q+0]);
        accS[4*q+1] = fmaf(s, x.y, accS[4*q+1]);
        accS[4*q+2] = fmaf(s, x.z, accS[4*q+2]);
        accS[4*q+3] = fmaf(s, x.w, accS[4*q+3]);
        accC[4*q+0] = fmaf(c, x.x, accC[4*q+0]);
        accC[4*q+1] = fmaf(c, x.y, accC[4*q+1]);
        accC[4*q+2] = fmaf(c, x.z, accC[4*q+2]);
        accC[4*q+3] = fmaf(c, x.w, accC[4*q+3]);
      }
    }
  }
  float* op = kvp + (size_t)bi * 8320;
  #pragma unroll
  for (int q = 0; q < 16; q++) {
    op[d*64 + mq + q]        = accS[q];
    op[4096 + d*64 + mq + q] = accC[q];
  }
  if (mq == 0) { op[8192 + d] = ksS; op[8256 + d] = ksC; }
}

// kvred + zf_cnt zeroing (cnt lives in mod-region slack, disjoint from all GEMM reads)
__global__ __launch_bounds__(256) void k_kvred(const float* __restrict__ kvp,
    float* __restrict__ kvb, int* __restrict__ cnt) {
  int bh = blockIdx.x;
  if (bh == 0 && threadIdx.x == 0) *cnt = 0;
  for (int i = threadIdx.x; i < 8320; i += 256) {
    float s = 0.f;
    #pragma unroll
    for (int c = 0; c < 8; c++) s += kvp[((size_t)bh*8 + c)*8320 + i];
    kvb[(size_t)bh*8320 + i] = s;
  }
}

// --- z = 1/max(sw*(q.ksS)+cw*(q.ksC), eps); flag |denom|<TAU for exact redo ---
__global__ __launch_bounds__(256) void k_z(const float* __restrict__ qr,
    const float* __restrict__ kvb, float* __restrict__ zb,
    int* __restrict__ list, int* __restrict__ cnt) {
  int bh = blockIdx.x >> 6, lc = blockIdx.x & 63;
  __shared__ float ksS_s[64], ksC_s[64];
  int t = threadIdx.x;
  if (t < 64) ksS_s[t] = kvb[(size_t)bh*8320 + 8192 + t];
  else if (t < 128) ksC_s[t-64] = kvb[(size_t)bh*8320 + 8256 + (t-64)];
  __syncthreads();
  int l = lc*64 + (t >> 2), part = t & 3;
  const float4* qp = (const float4*)(qr + ((size_t)bh*LL + l)*64 + part*16);
  float A = 0.f, Bv = 0.f;
  #pragma unroll
  for (int q = 0; q < 4; q++) {
    float4 x = qp[q];
    int kb = part*16 + 4*q;
    A  += x.x*ksS_s[kb] + x.y*ksS_s[kb+1] + x.z*ksS_s[kb+2] + x.w*ksS_s[kb+3];
    Bv += x.x*ksC_s[kb] + x.y*ksC_s[kb+1] + x.z*ksC_s[kb+2] + x.w*ksC_s[kb+3];
  }
  A  += __shfl_xor(A, 1, 64);  A  += __shfl_xor(A, 2, 64);
  Bv += __shfl_xor(Bv, 1, 64); Bv += __shfl_xor(Bv, 2, 64);
  if (part == 0) {
    float idxv = 1.5707964f * (float)(l + 1) * (1.0f/4096.0f);
    float denom = sinf(idxv)*A + cosf(idxv)*Bv;
    int gid = bh*LL + l;
    zb[gid] = 1.0f / fmaxf(denom, 1e-6f);
    if (fabsf(denom) < 0.05f) {
      int idx = atomicAdd(cnt, 1);
      if (idx < 8000) list[idx] = gid;
    }
  }
}

// --- exact z recompute for flagged rows: f32 x from h, f64 GEMV over Wq ---
__global__ __launch_bounds__(256) void k_zfix(const float* __restrict__ h,
    const float* __restrict__ rsig, const float* __restrict__ cf,
    const float* __restrict__ Wq,
    const float* __restrict__ cosT, const float* __restrict__ sinT,
    const float* __restrict__ kvb, const int* __restrict__ list,
    const int* __restrict__ cnt, float* __restrict__ zb) {
  __shared__ float xs[1024];
  __shared__ double qd[64];
  __shared__ double sq[64];
  int n = *cnt;
  if (n > 8000) n = 8000;
  int t = threadIdx.x;
  for (int i = blockIdx.x; i < n; i += gridDim.x) {
    int gid = list[i];
    int bh = gid >> 12, l = gid & 4095;
    int b = bh >> 4, hh = bh & 15;
    int row = b*4096 + l;
    float rs = rsig[row];
    const float* cfb = cf + (size_t)b*2048;
    for (int k = t; k < 1024; k += 256)
      xs[k] = fmaf(h[(size_t)row*1024 + k]*rs, cfb[k], cfb[1024 + k]);
    __syncthreads();
    int j = t >> 2, s = t & 3;
    const float* wrow = Wq + (size_t)(hh*64 + j)*1024 + s*256;
    double acc = 0.0;
    for (int k = 0; k < 256; k++)
      acc += (double)wrow[k] * (double)xs[s*256 + k];
    acc += __shfl_xor(acc, 1, 64);
    acc += __shfl_xor(acc, 2, 64);
    if (s == 0) qd[j] = acc;
    __syncthreads();
    if (t < 64) {
      double qv = qd[t];
      sq[t] = qv / (1.0 + exp(-qv));
    }
    __syncthreads();
    if (t == 0) {
      const float* cp = cosT + (size_t)l*64;
      const float* sp = sinT + (size_t)l*64;
      const float* ksS = kvb + (size_t)bh*8320 + 8192;
      const float* ksC = kvb + (size_t)bh*8320 + 8256;
      double dS = 0.0, dC = 0.0;
      for (int d = 0; d < 64; d++) {
        double rot = (d < 32) ? -sq[d + 32] : sq[d - 32];
        double qe = sq[d]*(double)cp[d] + rot*(double)sp[d];
        dS += qe * (double)ksS[d];
        dC += qe * (double)ksC[d];
      }
      double idxv = 1.5707963267948966 * (double)(l + 1) / 4096.0;
      float denom = (float)(sin(idxv)*dS + cos(idxv)*dC);
      zb[gid] = 1.0f / fmaxf(denom, 1e-6f);
    }
    __syncthreads();
  }
}

// --- attn numerator + z ---
__global__ __launch_bounds__(256) void k_attn(const float* __restrict__ qr,
    const float* __restrict__ kvb, const float* __restrict__ zb,
    unsigned short* __restrict__ attnb) {
  int bh = blockIdx.x >> 4, lc = blockIdx.x & 15;
  int t = threadIdx.x, w = t >> 6, lane = t & 63;
  const float* kvp_ = kvb + (size_t)bh*8320;
  float kvS[64], kvC[64];
  #pragma unroll
  for (int d = 0; d < 64; d++) kvS[d] = kvp_[d*64 + lane];
  #pragma unroll
  for (int d = 0; d < 64; d++) kvC[d] = kvp_[4096 + d*64 + lane];
  int b = bh >> 4, hh = bh & 15;
  int lbase = lc*256 + w*64;
  for (int li = 0; li < 64; li++) {
    int l = lbase + li;
    const float* qp = qr + ((size_t)bh*LL + l)*64;
    float qv = qp[lane];
    float z = zb[(size_t)bh*LL + l];
    float a0 = 0.f, a1 = 0.f, a2 = 0.f, a3 = 0.f;
    float b0 = 0.f, b1 = 0.f, b2 = 0.f, b3 = 0.f;
    #pragma unroll
    for (int d = 0; d < 64; d += 4) {
      float q0 = __uint_as_float(__builtin_amdgcn_readlane(__float_as_uint(qv), d+0));
      float q1 = __uint_as_float(__builtin_amdgcn_readlane(__float_as_uint(qv), d+1));
      float q2 = __uint_as_float(__builtin_amdgcn_readlane(__float_as_uint(qv), d+2));
      float q3 = __uint_as_float(__builtin_amdgcn_readlane(__float_as_uint(qv), d+3));
      a0 = fmaf(q0, kvS[d+0], a0);
      a1 = fmaf(q1, kvS[d+1], a1);
      a2 = fmaf(q2, kvS[d+2], a2);
      a3 = fmaf(q3, kvS[d+3], a3);
      b0 = fmaf(q0, kvC[d+0], b0);
      b1 = fmaf(q1, kvC[d+1], b1);
      b2 = fmaf(q2, kvC[d+2], b2);
      b3 = fmaf(q3, kvC[d+3], b3);
    }
    float A = (a0 + a1) + (a2 + a3);
    float Bv = (b0 + b1) + (b2 + b3);
    float idxv = 1.5707964f * (float)(l + 1) * (1.0f/4096.0f);
    float num = sinf(idxv)*A + cosf(idxv)*Bv;
    attnb[(((size_t)b*LL + l)*HH + hh)*64 + lane] = f2bf(num * z);
  }
}

extern "C" void kernel_launch(void* const* d_in, const int* in_sizes, int n_in,
                              void* d_out, int out_size, void* d_ws, size_t ws_size,
                              hipStream_t stream) {
  const float* h    = (const float*)d_in[0];
  const float* c    = (const float*)d_in[1];
  const float* cosT = (const float*)d_in[2];
  const float* sinT = (const float*)d_in[3];
  const float* Wq   = (const float*)d_in[4];
  const float* Wk   = (const float*)d_in[5];
  const float* Wv   = (const float*)d_in[6];
  const float* Wo   = (const float*)d_in[7];
  const float* Wg   = (const float*)d_in[8];
  const float* Wu   = (const float*)d_in[9];
  const float* Wd   = (const float*)d_in[10];
  const float* w1   = (const float*)d_in[11];
  const float* w2   = (const float*)d_in[12];
  const float* Wada = (const float*)d_in[13];
  const float* bada = (const float*)d_in[14];
  float* out = (float*)d_out;

  // ---- workspace layout (total 167,084,032 B, proven rounds 2/3/6/8/9) ----
  constexpr size_t BIG_SZ   = (size_t)MM * II * 2;          // 134,217,728
  constexpr size_t WS_NEEDED = BIG_SZ + 131072 + 32768*2 + 65536*2
      + 1048576 + 2129920 + 2097152*2 + 8388608*3;
  if (ws_size < WS_NEEDED) return;

  char* p = (char*)d_ws;
  char* big = p;                               p += BIG_SZ;
  float* mod = (float*)p;                      p += 131072;
  float* cf1 = (float*)p;                      p += 32768;
  float* cf2 = (float*)p;                      p += 32768;
  float* rsig1 = (float*)p;                    p += 65536;
  float* rsig2 = (float*)p;                    p += 65536;
  float* zb  = (float*)p;                      p += 1048576;
  float* kvb = (float*)p;                      p += 2129920;
  unsigned short* Wvb = (unsigned short*)p;    p += 2097152;
  unsigned short* Wob = (unsigned short*)p;    p += 2097152;
  unsigned short* Wgb = (unsigned short*)p;    p += 8388608;
  unsigned short* Wub = (unsigned short*)p;    p += 8388608;
  unsigned short* Wdb = (unsigned short*)p;    p += 8388608;
  // zf_cnt/zf_list live in mod-region slack: mod uses 6*EE*BB*4 = 98304 B of
  // 131072; GEMM epilogues read mod[< 98304] only. 32KB slack -> cnt + 8128 ids.
  int* zf_cnt  = (int*)((char*)mod + 98304);
  int* zf_list = zf_cnt + 64;
  // time-shared arena inside BIG (128 MiB). Lifetimes (strictly sequential,
  // round-9 proven):
  //   xh,xl   : [split1 .. k_qk]        (0-64M)
  //   vtb     : [V .. kvpart]           (64-96M)
  //   kvp     : [kvpart .. kvred]       (96-112.3M)
  //   qr      : [k_qk .. k_attn]        (64-128M)
  //   attnb   : [k_attn .. WO]          (0-64M region head)
  //   x2b     : [split2 .. GU]          (0-32M)
  //   Pb(half): [GU .. D]               (32-96M)
  unsigned short* xh   = (unsigned short*)big;
  unsigned short* xl   = (unsigned short*)(big + 33554432);
  unsigned short* vtb  = (unsigned short*)(big + 67108864);
  float* kvp           = (float*)(big + 100663296);
  float* qr            = (float*)(big + 67108864);
  unsigned short* attnb= (unsigned short*)big;
  unsigned short* x2b  = (unsigned short*)big;
  unsigned short* Pb   = (unsigned short*)(big + 33554432);
  float* kr            = (float*)d_out;

  k_mod<<<dim3(24, BB), 256, 0, stream>>>(c, Wada, bada, mod);
  k_coef<<<dim3(4, BB), 256, 0, stream>>>(mod, w1, w2, cf1, cf2);
  k_rsig<<<MM, 256, 0, stream>>>(h, rsig1);
  k_f2b<<<1024, 256, 0, stream>>>(Wv, Wvb, EE*EE/4);
  k_f2b<<<1024, 256, 0, stream>>>(Wo, Wob, EE*EE/4);
  k_f2b<<<4096, 256, 0, stream>>>(Wg, Wgb, II*EE/4);
  k_f2b<<<4096, 256, 0, stream>>>(Wu, Wub, II*EE/4);
  k_f2b<<<4096, 256, 0, stream>>>(Wd, Wdb, EE*II/4);
  k_split1<<<MM, 256, 0, stream>>>(h, rsig1, cf1, xh, xl);

  // K projection (f32 SGEMM 128x128, proven) -> kr (in d_out); V; kv reduction
  k_sgemmK<<<dim3(128, 8), 256, 0, stream>>>(h, Wk, rsig1, cf1, cosT, sinT, kr);
  k_gemm2<0, EE, EE, EE><<<dim3(128, 8), 256, 0, stream>>>(
      xh, Wvb, 0, 0, nullptr, nullptr, vtb, nullptr);
  k_kvpart<<<BB*HH*8, 256, 0, stream>>>(kr, vtb, kvp);
  k_kvred<<<BB*HH, 256, 0, stream>>>(kvp, kvb, zf_cnt);

  // Q projection (split-bf16) -> qr; z with flagging; exact fixup; attn
  k_qk<<<dim3(128, 16), 256, 0, stream>>>(xh, xl, Wq, cosT, sinT, qr);
  k_z<<<BB*HH*(LL/64), 256, 0, stream>>>(qr, kvb, zb, zf_list, zf_cnt);
  k_zfix<<<120, 256, 0, stream>>>(h, rsig1, cf1, Wq, cosT, sinT, kvb,
                                  zf_list, zf_cnt, zb);
  k_attn<<<BB*HH*(LL/256), 256, 0, stream>>>(qr, kvb, zb, attnb);

  // WO projection + residual -> out
  k_gemm2<1, EE, EE, EE><<<dim3(128, 8), 256, 0, stream>>>(
      attnb, Wob, 0, 0, h, mod, nullptr, out);

  // MLP: x2 precomputed bf16 once; fused G+U per half; D accumulates in-place.
  k_rsig<<<MM, 256, 0, stream>>>(out, rsig2);
  k_split2<<<MM, 256, 0, stream>>>(out, rsig2, cf2, x2b);
  for (int half = 0; half < 2; half++) {
    k_gemmGU<<<dim3(128, 16), 256, 0, stream>>>(
        x2b, Wgb, Wub, half*2048, Pb);
    k_gemm2<4, 2048, 2048, II><<<dim3(128, 8), 256, 0, stream>>>(
        Pb, Wdb, half*2048, 0, out, mod, nullptr, out);
  }
}

// Round 13
// 1991.400 us; speedup vs baseline: 1.0018x; 1.0018x over previous
//
#include <hip/hip_runtime.h>
#include <hip/hip_bf16.h>

#define BB 4
#define LL 4096
#define EE 1024
#define HH 16
#define II 4096
#define MM (BB*LL)

using f32x4 = __attribute__((ext_vector_type(4))) float;
using s16x8 = __attribute__((ext_vector_type(8))) short;
using u32x4 = __attribute__((ext_vector_type(4))) unsigned int;

__device__ __forceinline__ unsigned short f2bf(float f) {
  union { float f; unsigned u; } x; x.f = f;
  unsigned r = x.u + 0x7fffu + ((x.u >> 16) & 1u);
  return (unsigned short)(r >> 16);
}
__device__ __forceinline__ float bf2f(unsigned short s) {
  union { unsigned u; float f; } x; x.u = ((unsigned)s) << 16;
  return x.f;
}
__device__ __forceinline__ float silu_f(float x) { return x / (1.0f + expf(-x)); }

__device__ __forceinline__ void gll16(const void* g, void* l) {
  __builtin_amdgcn_global_load_lds(
      (const __attribute__((address_space(1))) unsigned int*)g,
      (__attribute__((address_space(3))) unsigned int*)l, 16, 0, 0);
}

// ---------------- adaLN modulation: mod = c @ Wada^T + bada ----------------
__global__ __launch_bounds__(256) void k_mod(const float* __restrict__ c,
    const float* __restrict__ Wada, const float* __restrict__ bada,
    float* __restrict__ mod) {
  __shared__ float cs[EE];
  int b = blockIdx.y;
  int n = blockIdx.x * 256 + threadIdx.x;
  for (int i = threadIdx.x; i < EE; i += 256) cs[i] = c[b*EE + i];
  __syncthreads();
  const float4* wp = (const float4*)(Wada + (size_t)n * EE);
  float acc = 0.f;
  for (int k = 0; k < EE/4; k++) {
    float4 t = wp[k];
    acc += t.x*cs[4*k] + t.y*cs[4*k+1] + t.z*cs[4*k+2] + t.w*cs[4*k+3];
  }
  mod[(size_t)b*6*EE + n] = acc + bada[n];
}

// ------------- coef: c1[b,k]=w[k]*(1+sc), c0[b,k]=sh, for both norms --------
__global__ __launch_bounds__(256) void k_coef(const float* __restrict__ mod,
    const float* __restrict__ w1, const float* __restrict__ w2,
    float* __restrict__ cf1, float* __restrict__ cf2) {
  int k = blockIdx.x * 256 + threadIdx.x;
  int b = blockIdx.y;
  const float* mb = mod + (size_t)b*6*EE;
  cf1[(size_t)b*2048 + k]        = w1[k] * (1.0f + mb[EE + k]);
  cf1[(size_t)b*2048 + 1024 + k] = mb[k];
  cf2[(size_t)b*2048 + k]        = w2[k] * (1.0f + mb[4*EE + k]);
  cf2[(size_t)b*2048 + 1024 + k] = mb[3*EE + k];
}

// ------------- rsig[row] = 1/sqrt(mean(x^2)+eps) ----------------
__global__ __launch_bounds__(256) void k_rsig(const float* __restrict__ in,
    float* __restrict__ rsig) {
  int row = blockIdx.x;
  int t = threadIdx.x;
  float4 v = ((const float4*)(in + (size_t)row * EE))[t];
  float ss = v.x*v.x + v.y*v.y + v.z*v.z + v.w*v.w;
  #pragma unroll
  for (int o = 32; o > 0; o >>= 1) ss += __shfl_down(ss, o, 64);
  __shared__ float red[4];
  if ((t & 63) == 0) red[t >> 6] = ss;
  __syncthreads();
  float tot = red[0] + red[1] + red[2] + red[3];
  if (t == 0) rsig[row] = 1.0f / sqrtf(tot * (1.0f/1024.0f) + 1e-6f);
}

// ---------------- f32 -> bf16 weight conversion ----------------
__global__ __launch_bounds__(256) void k_f2b(const float* __restrict__ s,
    unsigned short* __restrict__ d, int n4) {
  int i = blockIdx.x * 256 + threadIdx.x;
  if (i >= n4) return;
  float4 v = ((const float4*)s)[i];
  ushort4 u; u.x = f2bf(v.x); u.y = f2bf(v.y); u.z = f2bf(v.z); u.w = f2bf(v.w);
  ((ushort4*)d)[i] = u;
}

// ------------- x1 = modulate(rmsnorm(h)) -> split bf16 hi/lo ----------------
__global__ __launch_bounds__(256) void k_split1(const float* __restrict__ h,
    const float* __restrict__ rsig, const float* __restrict__ cf,
    unsigned short* __restrict__ xh, unsigned short* __restrict__ xl) {
  int row = blockIdx.x;
  int t = threadIdx.x;
  int b = row >> 12;
  float rs = rsig[row];
  const float* cfb = cf + (size_t)b*2048;
  float4 v  = ((const float4*)(h + (size_t)row*EE))[t];
  float4 c1 = ((const float4*)cfb)[t];
  float4 c0 = ((const float4*)(cfb + 1024))[t];
  float x0 = fmaf(v.x*rs, c1.x, c0.x);
  float x1 = fmaf(v.y*rs, c1.y, c0.y);
  float x2 = fmaf(v.z*rs, c1.z, c0.z);
  float x3 = fmaf(v.w*rs, c1.w, c0.w);
  ushort4 uh, ul;
  uh.x = f2bf(x0); ul.x = f2bf(x0 - bf2f(uh.x));
  uh.y = f2bf(x1); ul.y = f2bf(x1 - bf2f(uh.y));
  uh.z = f2bf(x2); ul.z = f2bf(x2 - bf2f(uh.z));
  uh.w = f2bf(x3); ul.w = f2bf(x3 - bf2f(uh.w));
  ((ushort4*)(xh + (size_t)row*EE))[t] = uh;
  ((ushort4*)(xl + (size_t)row*EE))[t] = ul;
}

// ------------- x2 = modulate(rmsnorm(h2)) -> bf16 ----------------
__global__ __launch_bounds__(256) void k_split2(const float* __restrict__ in,
    const float* __restrict__ rsig, const float* __restrict__ cf,
    unsigned short* __restrict__ xb) {
  int row = blockIdx.x;
  int t = threadIdx.x;
  int b = row >> 12;
  float rs = rsig[row];
  const float* cfb = cf + (size_t)b*2048;
  float4 v  = ((const float4*)(in + (size_t)row*EE))[t];
  float4 c1 = ((const float4*)cfb)[t];
  float4 c0 = ((const float4*)(cfb + 1024))[t];
  ushort4 u;
  u.x = f2bf(fmaf(v.x*rs, c1.x, c0.x));
  u.y = f2bf(fmaf(v.y*rs, c1.y, c0.y));
  u.z = f2bf(fmaf(v.z*rs, c1.z, c0.z));
  u.w = f2bf(fmaf(v.w*rs, c1.w, c0.w));
  ((ushort4*)(xb + (size_t)row*EE))[t] = u;
}

// ======================= mega-kernel role bodies ===========================
// Role K: f32 SGEMM 128x128 (bit-identical to rounds-2/6/8/9 proven kernel).
__device__ void role_sgemmK(char* smem, int bm, int bn,
    const float* __restrict__ Ah, const float* __restrict__ W,
    const float* __restrict__ rsig, const float* __restrict__ cf,
    const float* __restrict__ cosT, const float* __restrict__ sinT,
    float* __restrict__ outq) {
  float (*As)[128] = (float(*)[128])(smem);
  float (*Bs)[128] = (float(*)[128])(smem + 4096);
  float* c1s = (float*)(smem + 8192);
  float* c0s = (float*)(smem + 12288);
  int t = threadIdx.x;
  int tx = t & 15, ty = t >> 4;
  int srow = t >> 1, sk = (t & 1) * 4;
  int bidx = bm >> 5;
  for (int i = t; i < 1024; i += 256) {
    c1s[i] = cf[(size_t)bidx*2048 + i];
    c0s[i] = cf[(size_t)bidx*2048 + 1024 + i];
  }
  int arow = bm*128 + srow;
  float rsA = rsig[arow];
  const float* ap = Ah + (size_t)arow*EE + sk;
  const float* bp = W + (size_t)(bn*128 + srow)*EE + sk;
  float acc[8][8];
  #pragma unroll
  for (int i = 0; i < 8; i++)
    #pragma unroll
    for (int j = 0; j < 8; j++) acc[i][j] = 0.f;
  float4 pa = *(const float4*)ap;
  float4 pb = *(const float4*)bp;
  int c0 = (tx < 8) ? tx*4 : 64 + (tx - 8)*4;
  __syncthreads();
  for (int k0 = 0; k0 < EE; k0 += 8) {
    int kb = k0 + sk;
    As[sk+0][srow] = fmaf(pa.x*rsA, c1s[kb+0], c0s[kb+0]);
    As[sk+1][srow] = fmaf(pa.y*rsA, c1s[kb+1], c0s[kb+1]);
    As[sk+2][srow] = fmaf(pa.z*rsA, c1s[kb+2], c0s[kb+2]);
    As[sk+3][srow] = fmaf(pa.w*rsA, c1s[kb+3], c0s[kb+3]);
    Bs[sk+0][srow] = pb.x; Bs[sk+1][srow] = pb.y; Bs[sk+2][srow] = pb.z; Bs[sk+3][srow] = pb.w;
    __syncthreads();
    if (k0 + 8 < EE) {
      pa = *(const float4*)(ap + k0 + 8);
      pb = *(const float4*)(bp + k0 + 8);
    }
    #pragma unroll
    for (int k = 0; k < 8; k++) {
      float4 a0 = *(const float4*)&As[k][ty*8];
      float4 a1 = *(const float4*)&As[k][ty*8+4];
      float4 b0 = *(const float4*)&Bs[k][c0];
      float4 b1 = *(const float4*)&Bs[k][c0+32];
      float av[8] = {a0.x,a0.y,a0.z,a0.w,a1.x,a1.y,a1.z,a1.w};
      float bv[8]  = {b0.x,b0.y,b0.z,b0.w,b1.x,b1.y,b1.z,b1.w};
      #pragma unroll
      for (int i = 0; i < 8; i++)
        #pragma unroll
        for (int j = 0; j < 8; j++)
          acc[i][j] = fmaf(av[i], bv[j], acc[i][j]);
    }
    __syncthreads();
  }
  int head = bn*2 + (tx >= 8 ? 1 : 0);
  int d0 = (tx < 8) ? tx*4 : (tx - 8)*4;
  #pragma unroll
  for (int i = 0; i < 8; i++) {
    int m = bm*128 + ty*8 + i;
    int b = m >> 12, l = m & 4095;
    const float* cp = cosT + (size_t)l*64;
    const float* sp = sinT + (size_t)l*64;
    float4 cl  = *(const float4*)(cp + d0);
    float4 slv = *(const float4*)(sp + d0);
    float4 chv = *(const float4*)(cp + d0 + 32);
    float4 shv = *(const float4*)(sp + d0 + 32);
    float sA0 = silu_f(acc[i][0]), sA1 = silu_f(acc[i][1]), sA2 = silu_f(acc[i][2]), sA3 = silu_f(acc[i][3]);
    float sB0 = silu_f(acc[i][4]), sB1 = silu_f(acc[i][5]), sB2 = silu_f(acc[i][6]), sB3 = silu_f(acc[i][7]);
    float q00 = sA0*cl.x - sB0*slv.x;
    float q01 = sA1*cl.y - sB1*slv.y;
    float q02 = sA2*cl.z - sB2*slv.z;
    float q03 = sA3*cl.w - sB3*slv.w;
    float q10 = sB0*chv.x + sA0*shv.x;
    float q11 = sB1*chv.y + sA1*shv.y;
    float q12 = sB2*chv.z + sA2*shv.z;
    float q13 = sB3*chv.w + sA3*shv.w;
    float* op = outq + ((size_t)(b*HH + head)*LL + l)*64;
    *(float4*)(op + d0)      = make_float4(q00, q01, q02, q03);
    *(float4*)(op + d0 + 32) = make_float4(q10, q11, q12, q13);
  }
}

// Role V: bf16 MFMA 128x128, pure gload_lds (bit-identical to k_gemm2<0>).
__device__ void role_v(char* smem, int bm, int bn,
    const unsigned short* __restrict__ Ab, const unsigned short* __restrict__ Bw,
    unsigned short* __restrict__ outb) {
  unsigned short* As = (unsigned short*)smem;
  unsigned short* Bs = (unsigned short*)(smem + 8192);
  int t = threadIdx.x, w = t >> 6, lane = t & 63;
  int wm = (w >> 1) * 64, wn = (w & 1) * 64;
  int rin = lane >> 2, slot = lane & 3;
  int brow0 = w*32 + rin, brow1 = brow0 + 16;
  int swz0 = (((brow0>>1)&3) ^ slot) * 8;
  int swz1 = (((brow1>>1)&3) ^ slot) * 8;
  const unsigned short* ag0 = Ab + (size_t)(bm*128 + brow0)*EE + swz0;
  const unsigned short* ag1 = Ab + (size_t)(bm*128 + brow1)*EE + swz1;
  const unsigned short* bg0 = Bw + (size_t)(bn*128 + brow0)*EE + swz0;
  const unsigned short* bg1 = Bw + (size_t)(bn*128 + brow1)*EE + swz1;
  unsigned short* al0 = &As[(w*32 + 0) * 32];
  unsigned short* al1 = &As[(w*32 + 16) * 32];
  unsigned short* bl0 = &Bs[(w*32 + 0) * 32];
  unsigned short* bl1 = &Bs[(w*32 + 16) * 32];
  f32x4 acc[4][4];
  #pragma unroll
  for (int i = 0; i < 4; i++)
    #pragma unroll
    for (int j = 0; j < 4; j++) acc[i][j] = (f32x4){0.f, 0.f, 0.f, 0.f};
  int r16 = lane & 15, kg = lane >> 4;
  for (int k0 = 0; k0 < EE; k0 += 32) {
    gll16(ag0 + k0, al0);
    gll16(ag1 + k0, al1);
    gll16(bg0 + k0, bl0);
    gll16(bg1 + k0, bl1);
    __syncthreads();
    s16x8 af[4], bfr[4];
    #pragma unroll
    for (int i = 0; i < 4; i++) {
      int row = wm + i*16 + r16;
      af[i] = *(const s16x8*)&As[row*32 + ((((row>>1)&3) ^ kg) << 3)];
    }
    #pragma unroll
    for (int j = 0; j < 4; j++) {
      int row = wn + j*16 + r16;
      bfr[j] = *(const s16x8*)&Bs[row*32 + ((((row>>1)&3) ^ kg) << 3)];
    }
    #pragma unroll
    for (int i = 0; i < 4; i++)
      #pragma unroll
      for (int j = 0; j < 4; j++)
        acc[i][j] = __builtin_amdgcn_mfma_f32_16x16x32_bf16(af[i], bfr[j], acc[i][j], 0, 0, 0);
    __syncthreads();
  }
  #pragma unroll
  for (int i = 0; i < 4; i++) {
    #pragma unroll
    for (int j = 0; j < 4; j++) {
      int nn = bn*128 + wn + j*16 + r16;
      #pragma unroll
      for (int r = 0; r < 4; r++) {
        int mm = bm*128 + wm + i*16 + kg*4 + r;
        int b = mm >> 12, l = mm & 4095, hh = nn >> 6, dd = nn & 63;
        outb[(((size_t)(b*HH + hh))*LL + l)*64 + dd] = f2bf(acc[i][j][r]);
      }
    }
  }
}

// ---- mega: K (f32 VALU-bound) || V (MFMA/DMA-bound) — complementary pipes.
// bid&1: 0->K (1024 blocks), 1->V (1024 blocks). Outputs disjoint:
// kr in d_out, vtb at big+64..96M; inputs h/xh read-only.
__global__ __launch_bounds__(256) void k_megaKV(
    const float* __restrict__ h, const float* __restrict__ Wk,
    const float* __restrict__ rsig, const float* __restrict__ cf,
    const float* __restrict__ cosT, const float* __restrict__ sinT,
    float* __restrict__ kr,
    const unsigned short* __restrict__ xh,
    const unsigned short* __restrict__ Wvb, unsigned short* __restrict__ vtb) {
  __shared__ __align__(16) char smem[16384];
  int bid = blockIdx.x;
  int idx = bid >> 1;
  if ((bid & 1) == 0) {
    role_sgemmK(smem, idx & 127, idx >> 7, h, Wk, rsig, cf, cosT, sinT, kr);
  } else {
    role_v(smem, idx & 127, idx >> 7, xh, Wvb, vtb);
  }
}

// ------- Q projection: 3-term split-bf16 MFMA GEMM (frozen since r6) --------
__global__ __launch_bounds__(256) void k_qk(
    const unsigned short* __restrict__ xh, const unsigned short* __restrict__ xl,
    const float* __restrict__ W,
    const float* __restrict__ cosT, const float* __restrict__ sinT,
    float* __restrict__ outq) {
  __shared__ unsigned short Ah[128*32];
  __shared__ unsigned short Al[128*32];
  __shared__ unsigned short Bh[64*40];
  __shared__ unsigned short Bl[64*40];
  int t = threadIdx.x, w = t >> 6, lane = t & 63;
  int bm = blockIdx.x, bn = blockIdx.y;
  int wm = (w & 1) * 64;
  int wn = (w >> 1) * 16;
  int r16 = lane & 15, kg = lane >> 4;
  int rin = lane >> 2, slot = lane & 3;
  int ar0 = w*32 + rin, ar1 = ar0 + 16;
  const unsigned short* ahg0 = xh + (size_t)(bm*128 + ar0)*EE + (size_t)((((ar0>>1)&3) ^ slot) * 8);
  const unsigned short* ahg1 = xh + (size_t)(bm*128 + ar1)*EE + (size_t)((((ar1>>1)&3) ^ slot) * 8);
  const unsigned short* alg0 = xl + (size_t)(bm*128 + ar0)*EE + (size_t)((((ar0>>1)&3) ^ slot) * 8);
  const unsigned short* alg1 = xl + (size_t)(bm*128 + ar1)*EE + (size_t)((((ar1>>1)&3) ^ slot) * 8);
  unsigned short* ahl0 = &Ah[(w*32 + 0) * 32];
  unsigned short* ahl1 = &Ah[(w*32 + 16) * 32];
  unsigned short* all0 = &Al[(w*32 + 0) * 32];
  unsigned short* all1 = &Al[(w*32 + 16) * 32];
  int srow = t >> 2, koff = (t & 3) * 8;
  const float* bp = W + (size_t)(bn*64 + srow)*EE + koff;
  float4 pb0 = *(const float4*)(bp + 0);
  float4 pb1 = *(const float4*)(bp + 4);
  f32x4 acc[4][2];
  #pragma unroll
  for (int i = 0; i < 4; i++) { acc[i][0] = (f32x4){0,0,0,0}; acc[i][1] = (f32x4){0,0,0,0}; }

  for (int k0 = 0; k0 < EE; k0 += 32) {
    gll16(ahg0 + k0, ahl0);
    gll16(ahg1 + k0, ahl1);
    gll16(alg0 + k0, all0);
    gll16(alg1 + k0, all1);
    {
      unsigned short h0 = f2bf(pb0.x), h1 = f2bf(pb0.y), h2 = f2bf(pb0.z), h3 = f2bf(pb0.w);
      unsigned short h4 = f2bf(pb1.x), h5 = f2bf(pb1.y), h6 = f2bf(pb1.z), h7 = f2bf(pb1.w);
      unsigned short l0 = f2bf(pb0.x - bf2f(h0)), l1 = f2bf(pb0.y - bf2f(h1));
      unsigned short l2 = f2bf(pb0.z - bf2f(h2)), l3 = f2bf(pb0.w - bf2f(h3));
      unsigned short l4 = f2bf(pb1.x - bf2f(h4)), l5 = f2bf(pb1.y - bf2f(h5));
      unsigned short l6 = f2bf(pb1.z - bf2f(h6)), l7 = f2bf(pb1.w - bf2f(h7));
      u32x4 uh, ul;
      uh[0] = ((unsigned)h1<<16)|h0; uh[1] = ((unsigned)h3<<16)|h2;
      uh[2] = ((unsigned)h5<<16)|h4; uh[3] = ((unsigned)h7<<16)|h6;
      ul[0] = ((unsigned)l1<<16)|l0; ul[1] = ((unsigned)l3<<16)|l2;
      ul[2] = ((unsigned)l5<<16)|l4; ul[3] = ((unsigned)l7<<16)|l6;
      *(u32x4*)&Bh[srow*40 + koff] = uh;
      *(u32x4*)&Bl[srow*40 + koff] = ul;
    }
    __syncthreads();
    if (k0 + 32 < EE) {
      pb0 = *(const float4*)(bp + k0 + 32);
      pb1 = *(const float4*)(bp + k0 + 36);
    }
    int brow0 = wn + r16, brow1 = wn + 32 + r16;
    s16x8 bh0 = *(const s16x8*)&Bh[brow0*40 + kg*8];
    s16x8 bl0 = *(const s16x8*)&Bl[brow0*40 + kg*8];
    s16x8 bh1 = *(const s16x8*)&Bh[brow1*40 + kg*8];
    s16x8 bl1 = *(const s16x8*)&Bl[brow1*40 + kg*8];
    #pragma unroll
    for (int i = 0; i < 4; i++) {
      int row = wm + i*16 + r16;
      int sw = ((((row>>1)&3) ^ kg) << 3);
      s16x8 ah = *(const s16x8*)&Ah[row*32 + sw];
      s16x8 al = *(const s16x8*)&Al[row*32 + sw];
      acc[i][0] = __builtin_amdgcn_mfma_f32_16x16x32_bf16(ah, bh0, acc[i][0], 0, 0, 0);
      acc[i][0] = __builtin_amdgcn_mfma_f32_16x16x32_bf16(ah, bl0, acc[i][0], 0, 0, 0);
      acc[i][0] = __builtin_amdgcn_mfma_f32_16x16x32_bf16(al, bh0, acc[i][0], 0, 0, 0);
      acc[i][1] = __builtin_amdgcn_mfma_f32_16x16x32_bf16(ah, bh1, acc[i][1], 0, 0, 0);
      acc[i][1] = __builtin_amdgcn_mfma_f32_16x16x32_bf16(ah, bl1, acc[i][1], 0, 0, 0);
      acc[i][1] = __builtin_amdgcn_mfma_f32_16x16x32_bf16(al, bh1, acc[i][1], 0, 0, 0);
    }
    __syncthreads();
  }
  int d = wn + r16;
  #pragma unroll
  for (int i = 0; i < 4; i++) {
    #pragma unroll
    for (int r = 0; r < 4; r++) {
      int mm = bm*128 + wm + i*16 + kg*4 + r;
      int b = mm >> 12, l = mm & 4095;
      const float* cp = cosT + (size_t)l*64;
      const float* sp = sinT + (size_t)l*64;
      float sl = silu_f(acc[i][0][r]);
      float sh = silu_f(acc[i][1][r]);
      float qlo = sl*cp[d]      - sh*sp[d];
      float qhi = sh*cp[d + 32] + sl*sp[d + 32];
      float* op = outq + (((size_t)(b*HH + bn))*LL + l)*64;
      op[d]      = qlo;
      op[d + 32] = qhi;
    }
  }
}

// ---- bf16 MFMA GEMM, pure global_load_lds both sides, 128x128 tile.
// EPI: 0=V(bf16 (B,H,L,64)) 1=WO(out=res+g1*acc) 2=G(Pb=silu bf16, stride 2048)
//      3=U(Pb*=acc in place)  4=D(out=res+g2*acc, res==out in-place add)
template<int EPI, int KLEN, int SA, int SB>
__global__ __launch_bounds__(256) void k_gemm2(
    const unsigned short* __restrict__ Ab,
    const unsigned short* __restrict__ Bw,
    int kbB, int bnoff,
    const float* __restrict__ res, const float* __restrict__ mod,
    unsigned short* __restrict__ outb, float* __restrict__ outf) {
  __shared__ unsigned short As[128 * 32];
  __shared__ unsigned short Bs[128 * 32];
  int t = threadIdx.x, w = t >> 6, lane = t & 63;
  int bm = blockIdx.x, bn = blockIdx.y;
  int wm = (w >> 1) * 64, wn = (w & 1) * 64;
  int rin = lane >> 2, slot = lane & 3;
  int brow0 = w*32 + rin, brow1 = brow0 + 16;
  int swz0 = (((brow0>>1)&3) ^ slot) * 8;
  int swz1 = (((brow1>>1)&3) ^ slot) * 8;
  const unsigned short* ag0 = Ab + (size_t)(bm*128 + brow0)*SA + swz0;
  const unsigned short* ag1 = Ab + (size_t)(bm*128 + brow1)*SA + swz1;
  const unsigned short* bg0 = Bw + (size_t)(bnoff + bn*128 + brow0)*SB + kbB + swz0;
  const unsigned short* bg1 = Bw + (size_t)(bnoff + bn*128 + brow1)*SB + kbB + swz1;
  unsigned short* al0 = &As[(w*32 + 0) * 32];
  unsigned short* al1 = &As[(w*32 + 16) * 32];
  unsigned short* bl0 = &Bs[(w*32 + 0) * 32];
  unsigned short* bl1 = &Bs[(w*32 + 16) * 32];
  f32x4 acc[4][4];
  #pragma unroll
  for (int i = 0; i < 4; i++)
    #pragma unroll
    for (int j = 0; j < 4; j++) acc[i][j] = (f32x4){0.f, 0.f, 0.f, 0.f};
  int r16 = lane & 15, kg = lane >> 4;
  for (int k0 = 0; k0 < KLEN; k0 += 32) {
    gll16(ag0 + k0, al0);
    gll16(ag1 + k0, al1);
    gll16(bg0 + k0, bl0);
    gll16(bg1 + k0, bl1);
    __syncthreads();
    s16x8 af[4], bfr[4];
    #pragma unroll
    for (int i = 0; i < 4; i++) {
      int row = wm + i*16 + r16;
      af[i] = *(const s16x8*)&As[row*32 + ((((row>>1)&3) ^ kg) << 3)];
    }
    #pragma unroll
    for (int j = 0; j < 4; j++) {
      int row = wn + j*16 + r16;
      bfr[j] = *(const s16x8*)&Bs[row*32 + ((((row>>1)&3) ^ kg) << 3)];
    }
    #pragma unroll
    for (int i = 0; i < 4; i++)
      #pragma unroll
      for (int j = 0; j < 4; j++)
        acc[i][j] = __builtin_amdgcn_mfma_f32_16x16x32_bf16(af[i], bfr[j], acc[i][j], 0, 0, 0);
    __syncthreads();
  }
  #pragma unroll
  for (int i = 0; i < 4; i++) {
    #pragma unroll
    for (int j = 0; j < 4; j++) {
      int nn = bn*128 + wn + j*16 + r16;
      #pragma unroll
      for (int r = 0; r < 4; r++) {
        int mm = bm*128 + wm + i*16 + kg*4 + r;
        float v = acc[i][j][r];
        if constexpr (EPI == 0) {
          int b = mm >> 12, l = mm & 4095, hh = nn >> 6, dd = nn & 63;
          outb[(((size_t)(b*HH + hh))*LL + l)*64 + dd] = f2bf(v);
        } else if constexpr (EPI == 1) {
          int b = mm >> 12;
          size_t o = (size_t)mm*EE + nn;
          outf[o] = res[o] + mod[(size_t)b*6*EE + 2*EE + nn] * v;
        } else if constexpr (EPI == 2) {
          outb[(size_t)mm*2048 + nn] = f2bf(silu_f(v));
        } else if constexpr (EPI == 3) {
          size_t o = (size_t)mm*2048 + nn;
          outb[o] = f2bf(bf2f(outb[o]) * v);
        } else {
          int b = mm >> 12;
          size_t o = (size_t)mm*EE + nn;
          outf[o] = res[o] + mod[(size_t)b*6*EE + 5*EE + nn] * v;
        }
      }
    }
  }
}

// ---- kv partials over 512-l chunks ----
__global__ __launch_bounds__(256) void k_kvpart(const float* __restrict__ kr,
    const unsigned short* __restrict__ vtb, float* __restrict__ kvp) {
  int bi = blockIdx.x;
  int bh = bi >> 3, ch = bi & 7;
  const float* kp = kr + ((size_t)bh*LL + ch*512)*64;
  const unsigned short* vp = vtb + ((size_t)bh*LL + ch*512)*64;
  __shared__ float k8[8][64];
  __shared__ float v8[8][64];
  __shared__ float sw8[8], cw8[8];
  int t = threadIdx.x;
  int d = t >> 2, mq = (t & 3) * 16;
  float accS[16], accC[16];
  #pragma unroll
  for (int q = 0; q < 16; q++) { accS[q] = 0.f; accC[q] = 0.f; }
  float ksS = 0.f, ksC = 0.f;
  for (int l0 = 0; l0 < 512; l0 += 8) {
    __syncthreads();
    #pragma unroll
    for (int rep = 0; rep < 2; rep++) {
      int idx = rep*256 + t;
      k8[idx>>6][idx&63] = kp[(size_t)(l0 + (idx>>6))*64 + (idx&63)];
      v8[idx>>6][idx&63] = bf2f(vp[(size_t)(l0 + (idx>>6))*64 + (idx&63)]);
    }
    if (t < 8) {
      int gl = ch*512 + l0 + t;
      float idxv = 1.5707964f * (float)(gl + 1) * (1.0f/4096.0f);
      sw8[t] = sinf(idxv);
      cw8[t] = cosf(idxv);
    }
    __syncthreads();
    #pragma unroll
    for (int l = 0; l < 8; l++) {
      float kd = k8[l][d];
      float s = kd * sw8[l];
      float c = kd * cw8[l];
      ksS += s; ksC += c;
      const float4* vv = (const float4*)&v8[l][mq];
      #pragma unroll
      for (int q = 0; q < 4; q++) {
        float4 x = vv[q];
        accS[4*q+0] = fmaf(s, x.x, accS[4*q+0]);
        accS[4*q+1] = fmaf(s, x.y, accS[4*q+1]);
        accS[4*q+2] = fmaf(s, x.z, accS[4*q+2]);
        accS[4*q+3] = fmaf(s, x.w, accS[4*q+3]);
        accC[4*q+0] = fmaf(c, x.x, accC[4*q+0]);
        accC[4*q+1] = fmaf(c, x.y, accC[4*q+1]);
        accC[4*q+2] = fmaf(c, x.z, accC[4*q+2]);
        accC[4*q+3] = fmaf(c, x.w, accC[4*q+3]);
      }
    }
  }
  float* op = kvp + (size_t)bi * 8320;
  #pragma unroll
  for (int q = 0; q < 16; q++) {
    op[d*64 + mq + q]        = accS[q];
    op[4096 + d*64 + mq + q] = accC[q];
  }
  if (mq == 0) { op[8192 + d] = ksS; op[8256 + d] = ksC; }
}

// kvred + zf_cnt zeroing (cnt lives in mod-region slack, validated in r12)
__global__ __launch_bounds__(256) void k_kvred(const float* __restrict__ kvp,
    float* __restrict__ kvb, int* __restrict__ cnt) {
  int bh = blockIdx.x;
  if (bh == 0 && threadIdx.x == 0) *cnt = 0;
  for (int i = threadIdx.x; i < 8320; i += 256) {
    float s = 0.f;
    #pragma unroll
    for (int c = 0; c < 8; c++) s += kvp[((size_t)bh*8 + c)*8320 + i];
    kvb[(size_t)bh*8320 + i] = s;
  }
}

// --- z = 1/max(sw*(q.ksS)+cw*(q.ksC), eps); flag |denom|<TAU for exact redo ---
__global__ __launch_bounds__(256) void k_z(const float* __restrict__ qr,
    const float* __restrict__ kvb, float* __restrict__ zb,
    int* __restrict__ list, int* __restrict__ cnt) {
  int bh = blockIdx.x >> 6, lc = blockIdx.x & 63;
  __shared__ float ksS_s[64], ksC_s[64];
  int t = threadIdx.x;
  if (t < 64) ksS_s[t] = kvb[(size_t)bh*8320 + 8192 + t];
  else if (t < 128) ksC_s[t-64] = kvb[(size_t)bh*8320 + 8256 + (t-64)];
  __syncthreads();
  int l = lc*64 + (t >> 2), part = t & 3;
  const float4* qp = (const float4*)(qr + ((size_t)bh*LL + l)*64 + part*16);
  float A = 0.f, Bv = 0.f;
  #pragma unroll
  for (int q = 0; q < 4; q++) {
    float4 x = qp[q];
    int kb = part*16 + 4*q;
    A  += x.x*ksS_s[kb] + x.y*ksS_s[kb+1] + x.z*ksS_s[kb+2] + x.w*ksS_s[kb+3];
    Bv += x.x*ksC_s[kb] + x.y*ksC_s[kb+1] + x.z*ksC_s[kb+2] + x.w*ksC_s[kb+3];
  }
  A  += __shfl_xor(A, 1, 64);  A  += __shfl_xor(A, 2, 64);
  Bv += __shfl_xor(Bv, 1, 64); Bv += __shfl_xor(Bv, 2, 64);
  if (part == 0) {
    float idxv = 1.5707964f * (float)(l + 1) * (1.0f/4096.0f);
    float denom = sinf(idxv)*A + cosf(idxv)*Bv;
    int gid = bh*LL + l;
    zb[gid] = 1.0f / fmaxf(denom, 1e-6f);
    if (fabsf(denom) < 0.05f) {
      int idx = atomicAdd(cnt, 1);
      if (idx < 8000) list[idx] = gid;
    }
  }
}

// --- exact z recompute for flagged rows: f32 x from h, f64 GEMV over Wq ---
__global__ __launch_bounds__(256) void k_zfix(const float* __restrict__ h,
    const float* __restrict__ rsig, const float* __restrict__ cf,
    const float* __restrict__ Wq,
    const float* __restrict__ cosT, const float* __restrict__ sinT,
    const float* __restrict__ kvb, const int* __restrict__ list,
    const int* __restrict__ cnt, float* __restrict__ zb) {
  __shared__ float xs[1024];
  __shared__ double qd[64];
  __shared__ double sq[64];
  int n = *cnt;
  if (n > 8000) n = 8000;
  int t = threadIdx.x;
  for (int i = blockIdx.x; i < n; i += gridDim.x) {
    int gid = list[i];
    int bh = gid >> 12, l = gid & 4095;
    int b = bh >> 4, hh = bh & 15;
    int row = b*4096 + l;
    float rs = rsig[row];
    const float* cfb = cf + (size_t)b*2048;
    for (int k = t; k < 1024; k += 256)
      xs[k] = fmaf(h[(size_t)row*1024 + k]*rs, cfb[k], cfb[1024 + k]);
    __syncthreads();
    int j = t >> 2, s = t & 3;
    const float* wrow = Wq + (size_t)(hh*64 + j)*1024 + s*256;
    double acc = 0.0;
    for (int k = 0; k < 256; k++)
      acc += (double)wrow[k] * (double)xs[s*256 + k];
    acc += __shfl_xor(acc, 1, 64);
    acc += __shfl_xor(acc, 2, 64);
    if (s == 0) qd[j] = acc;
    __syncthreads();
    if (t < 64) {
      double qv = qd[t];
      sq[t] = qv / (1.0 + exp(-qv));
    }
    __syncthreads();
    if (t == 0) {
      const float* cp = cosT + (size_t)l*64;
      const float* sp = sinT + (size_t)l*64;
      const float* ksS = kvb + (size_t)bh*8320 + 8192;
      const float* ksC = kvb + (size_t)bh*8320 + 8256;
      double dS = 0.0, dC = 0.0;
      for (int d = 0; d < 64; d++) {
        double rot = (d < 32) ? -sq[d + 32] : sq[d - 32];
        double qe = sq[d]*(double)cp[d] + rot*(double)sp[d];
        dS += qe * (double)ksS[d];
        dC += qe * (double)ksC[d];
      }
      double idxv = 1.5707963267948966 * (double)(l + 1) / 4096.0;
      float denom = (float)(sin(idxv)*dS + cos(idxv)*dC);
      zb[gid] = 1.0f / fmaxf(denom, 1e-6f);
    }
    __syncthreads();
  }
}

// --- attn numerator + z ---
__global__ __launch_bounds__(256) void k_attn(const float* __restrict__ qr,
    const float* __restrict__ kvb, const float* __restrict__ zb,
    unsigned short* __restrict__ attnb) {
  int bh = blockIdx.x >> 4, lc = blockIdx.x & 15;
  int t = threadIdx.x, w = t >> 6, lane = t & 63;
  const float* kvp_ = kvb + (size_t)bh*8320;
  float kvS[64], kvC[64];
  #pragma unroll
  for (int d = 0; d < 64; d++) kvS[d] = kvp_[d*64 + lane];
  #pragma unroll
  for (int d = 0; d < 64; d++) kvC[d] = kvp_[4096 + d*64 + lane];
  int b = bh >> 4, hh = bh & 15;
  int lbase = lc*256 + w*64;
  for (int li = 0; li < 64; li++) {
    int l = lbase + li;
    const float* qp = qr + ((size_t)bh*LL + l)*64;
    float qv = qp[lane];
    float z = zb[(size_t)bh*LL + l];
    float a0 = 0.f, a1 = 0.f, a2 = 0.f, a3 = 0.f;
    float b0 = 0.f, b1 = 0.f, b2 = 0.f, b3 = 0.f;
    #pragma unroll
    for (int d = 0; d < 64; d += 4) {
      float q0 = __uint_as_float(__builtin_amdgcn_readlane(__float_as_uint(qv), d+0));
      float q1 = __uint_as_float(__builtin_amdgcn_readlane(__float_as_uint(qv), d+1));
      float q2 = __uint_as_float(__builtin_amdgcn_readlane(__float_as_uint(qv), d+2));
      float q3 = __uint_as_float(__builtin_amdgcn_readlane(__float_as_uint(qv), d+3));
      a0 = fmaf(q0, kvS[d+0], a0);
      a1 = fmaf(q1, kvS[d+1], a1);
      a2 = fmaf(q2, kvS[d+2], a2);
      a3 = fmaf(q3, kvS[d+3], a3);
      b0 = fmaf(q0, kvC[d+0], b0);
      b1 = fmaf(q1, kvC[d+1], b1);
      b2 = fmaf(q2, kvC[d+2], b2);
      b3 = fmaf(q3, kvC[d+3], b3);
    }
    float A = (a0 + a1) + (a2 + a3);
    float Bv = (b0 + b1) + (b2 + b3);
    float idxv = 1.5707964f * (float)(l + 1) * (1.0f/4096.0f);
    float num = sinf(idxv)*A + cosf(idxv)*Bv;
    attnb[(((size_t)b*LL + l)*HH + hh)*64 + lane] = f2bf(num * z);
  }
}

extern "C" void kernel_launch(void* const* d_in, const int* in_sizes, int n_in,
                              void* d_out, int out_size, void* d_ws, size_t ws_size,
                              hipStream_t stream) {
  const float* h    = (const float*)d_in[0];
  const float* c    = (const float*)d_in[1];
  const float* cosT = (const float*)d_in[2];
  const float* sinT = (const float*)d_in[3];
  const float* Wq   = (const float*)d_in[4];
  const float* Wk   = (const float*)d_in[5];
  const float* Wv   = (const float*)d_in[6];
  const float* Wo   = (const float*)d_in[7];
  const float* Wg   = (const float*)d_in[8];
  const float* Wu   = (const float*)d_in[9];
  const float* Wd   = (const float*)d_in[10];
  const float* w1   = (const float*)d_in[11];
  const float* w2   = (const float*)d_in[12];
  const float* Wada = (const float*)d_in[13];
  const float* bada = (const float*)d_in[14];
  float* out = (float*)d_out;

  // ---- workspace layout (total 167,084,032 B, proven rounds 2..12) ----
  constexpr size_t BIG_SZ   = (size_t)MM * II * 2;          // 134,217,728
  constexpr size_t WS_NEEDED = BIG_SZ + 131072 + 32768*2 + 65536*2
      + 1048576 + 2129920 + 2097152*2 + 8388608*3;
  if (ws_size < WS_NEEDED) return;

  char* p = (char*)d_ws;
  char* big = p;                               p += BIG_SZ;
  float* mod = (float*)p;                      p += 131072;
  float* cf1 = (float*)p;                      p += 32768;
  float* cf2 = (float*)p;                      p += 32768;
  float* rsig1 = (float*)p;                    p += 65536;
  float* rsig2 = (float*)p;                    p += 65536;
  float* zb  = (float*)p;                      p += 1048576;
  float* kvb = (float*)p;                      p += 2129920;
  unsigned short* Wvb = (unsigned short*)p;    p += 2097152;
  unsigned short* Wob = (unsigned short*)p;    p += 2097152;
  unsigned short* Wgb = (unsigned short*)p;    p += 8388608;
  unsigned short* Wub = (unsigned short*)p;    p += 8388608;
  unsigned short* Wdb = (unsigned short*)p;    p += 8388608;
  // zf_cnt/zf_list in mod-region slack (mod uses 98304 of 131072 B; validated r12)
  int* zf_cnt  = (int*)((char*)mod + 98304);
  int* zf_list = zf_cnt + 64;
  // time-shared arena inside BIG (128 MiB), round-9-proven lifetimes:
  //   xh,xl   : [split1 .. k_qk]        (0-64M)
  //   vtb     : [megaKV .. kvpart]      (64-96M)
  //   kvp     : [kvpart .. kvred]       (96-112.3M)
  //   qr      : [k_qk .. k_attn]        (64-128M)
  //   attnb   : [k_attn .. WO]          (0-64M head)
  //   x2b     : [split2 .. GU]          (0-32M)
  //   Pb(half): [G .. D]                (32-96M)
  unsigned short* xh   = (unsigned short*)big;
  unsigned short* xl   = (unsigned short*)(big + 33554432);
  unsigned short* vtb  = (unsigned short*)(big + 67108864);
  float* kvp           = (float*)(big + 100663296);
  float* qr            = (float*)(big + 67108864);
  unsigned short* attnb= (unsigned short*)big;
  unsigned short* x2b  = (unsigned short*)big;
  unsigned short* Pb   = (unsigned short*)(big + 33554432);
  float* kr            = (float*)d_out;

  k_mod<<<dim3(24, BB), 256, 0, stream>>>(c, Wada, bada, mod);
  k_coef<<<dim3(4, BB), 256, 0, stream>>>(mod, w1, w2, cf1, cf2);
  k_rsig<<<MM, 256, 0, stream>>>(h, rsig1);
  k_f2b<<<1024, 256, 0, stream>>>(Wv, Wvb, EE*EE/4);
  k_f2b<<<1024, 256, 0, stream>>>(Wo, Wob, EE*EE/4);
  k_f2b<<<4096, 256, 0, stream>>>(Wg, Wgb, II*EE/4);
  k_f2b<<<4096, 256, 0, stream>>>(Wu, Wub, II*EE/4);
  k_f2b<<<4096, 256, 0, stream>>>(Wd, Wdb, EE*II/4);
  k_split1<<<MM, 256, 0, stream>>>(h, rsig1, cf1, xh, xl);

  // K (f32 VALU) || V (MFMA/DMA) co-scheduled — complementary pipes (m114).
  // Outputs disjoint: kr in d_out, vtb at big+64..96M. Bodies = r9 kernels.
  k_megaKV<<<2048, 256, 0, stream>>>(h, Wk, rsig1, cf1, cosT, sinT, kr,
                                     xh, Wvb, vtb);

  k_kvpart<<<BB*HH*8, 256, 0, stream>>>(kr, vtb, kvp);
  k_kvred<<<BB*HH, 256, 0, stream>>>(kvp, kvb, zf_cnt);

  // Q projection (split-bf16) -> qr; z with flagging; exact fixup; attn
  k_qk<<<dim3(128, 16), 256, 0, stream>>>(xh, xl, Wq, cosT, sinT, qr);
  k_z<<<BB*HH*(LL/64), 256, 0, stream>>>(qr, kvb, zb, zf_list, zf_cnt);
  k_zfix<<<120, 256, 0, stream>>>(h, rsig1, cf1, Wq, cosT, sinT, kvb,
                                  zf_list, zf_cnt, zb);
  k_attn<<<BB*HH*(LL/256), 256, 0, stream>>>(qr, kvb, zb, attnb);

  // WO projection + residual -> out
  k_gemm2<1, EE, EE, EE><<<dim3(128, 8), 256, 0, stream>>>(
      attnb, Wob, 0, 0, h, mod, nullptr, out);

  // MLP: x2 precomputed bf16 once; separate G/U/D per half (r9-proven).
  k_rsig<<<MM, 256, 0, stream>>>(out, rsig2);
  k_split2<<<MM, 256, 0, stream>>>(out, rsig2, cf2, x2b);
  for (int half = 0; half < 2; half++) {
    k_gemm2<2, EE, EE, EE><<<dim3(128, 16), 256, 0, stream>>>(
        x2b, Wgb, 0, half*2048, nullptr, nullptr, Pb, nullptr);
    k_gemm2<3, EE, EE, EE><<<dim3(128, 16), 256, 0, stream>>>(
        x2b, Wub, 0, half*2048, nullptr, nullptr, Pb, nullptr);
    k_gemm2<4, 2048, 2048, II><<<dim3(128, 8), 256, 0, stream>>>(
        Pb, Wdb, half*2048, 0, out, mod, nullptr, out);
  }
}

// Round 14
// 1764.294 us; speedup vs baseline: 1.1308x; 1.1287x over previous
//
#include <hip/hip_runtime.h>
#include <hip/hip_bf16.h>

#define BB 4
#define LL 4096
#define EE 1024
#define HH 16
#define II 4096
#define MM (BB*LL)

using f32x4 = __attribute__((ext_vector_type(4))) float;
using s16x8 = __attribute__((ext_vector_type(8))) short;
using u32x4 = __attribute__((ext_vector_type(4))) unsigned int;

__device__ __forceinline__ unsigned short f2bf(float f) {
  union { float f; unsigned u; } x; x.f = f;
  unsigned r = x.u + 0x7fffu + ((x.u >> 16) & 1u);
  return (unsigned short)(r >> 16);
}
__device__ __forceinline__ float bf2f(unsigned short s) {
  union { unsigned u; float f; } x; x.u = ((unsigned)s) << 16;
  return x.f;
}
__device__ __forceinline__ float silu_f(float x) { return x / (1.0f + expf(-x)); }

__device__ __forceinline__ void gll16(const void* g, void* l) {
  __builtin_amdgcn_global_load_lds(
      (const __attribute__((address_space(1))) unsigned int*)g,
      (__attribute__((address_space(3))) unsigned int*)l, 16, 0, 0);
}

// ---------------- adaLN modulation: mod = c @ Wada^T + bada ----------------
__global__ __launch_bounds__(256) void k_mod(const float* __restrict__ c,
    const float* __restrict__ Wada, const float* __restrict__ bada,
    float* __restrict__ mod) {
  __shared__ float cs[EE];
  int b = blockIdx.y;
  int n = blockIdx.x * 256 + threadIdx.x;
  for (int i = threadIdx.x; i < EE; i += 256) cs[i] = c[b*EE + i];
  __syncthreads();
  const float4* wp = (const float4*)(Wada + (size_t)n * EE);
  float acc = 0.f;
  for (int k = 0; k < EE/4; k++) {
    float4 t = wp[k];
    acc += t.x*cs[4*k] + t.y*cs[4*k+1] + t.z*cs[4*k+2] + t.w*cs[4*k+3];
  }
  mod[(size_t)b*6*EE + n] = acc + bada[n];
}

// ------------- coef: c1[b,k]=w[k]*(1+sc), c0[b,k]=sh, for both norms --------
__global__ __launch_bounds__(256) void k_coef(const float* __restrict__ mod,
    const float* __restrict__ w1, const float* __restrict__ w2,
    float* __restrict__ cf1, float* __restrict__ cf2) {
  int k = blockIdx.x * 256 + threadIdx.x;
  int b = blockIdx.y;
  const float* mb = mod + (size_t)b*6*EE;
  cf1[(size_t)b*2048 + k]        = w1[k] * (1.0f + mb[EE + k]);
  cf1[(size_t)b*2048 + 1024 + k] = mb[k];
  cf2[(size_t)b*2048 + k]        = w2[k] * (1.0f + mb[4*EE + k]);
  cf2[(size_t)b*2048 + 1024 + k] = mb[3*EE + k];
}

// ------------- rsig[row] = 1/sqrt(mean(x^2)+eps) ----------------
__global__ __launch_bounds__(256) void k_rsig(const float* __restrict__ in,
    float* __restrict__ rsig) {
  int row = blockIdx.x;
  int t = threadIdx.x;
  float4 v = ((const float4*)(in + (size_t)row * EE))[t];
  float ss = v.x*v.x + v.y*v.y + v.z*v.z + v.w*v.w;
  #pragma unroll
  for (int o = 32; o > 0; o >>= 1) ss += __shfl_down(ss, o, 64);
  __shared__ float red[4];
  if ((t & 63) == 0) red[t >> 6] = ss;
  __syncthreads();
  float tot = red[0] + red[1] + red[2] + red[3];
  if (t == 0) rsig[row] = 1.0f / sqrtf(tot * (1.0f/1024.0f) + 1e-6f);
}

// ---------------- f32 -> bf16 weight conversion ----------------
__global__ __launch_bounds__(256) void k_f2b(const float* __restrict__ s,
    unsigned short* __restrict__ d, int n4) {
  int i = blockIdx.x * 256 + threadIdx.x;
  if (i >= n4) return;
  float4 v = ((const float4*)s)[i];
  ushort4 u; u.x = f2bf(v.x); u.y = f2bf(v.y); u.z = f2bf(v.z); u.w = f2bf(v.w);
  ((ushort4*)d)[i] = u;
}

// ------------- x1 = modulate(rmsnorm(h)) -> split bf16 hi/lo ----------------
__global__ __launch_bounds__(256) void k_split1(const float* __restrict__ h,
    const float* __restrict__ rsig, const float* __restrict__ cf,
    unsigned short* __restrict__ xh, unsigned short* __restrict__ xl) {
  int row = blockIdx.x;
  int t = threadIdx.x;
  int b = row >> 12;
  float rs = rsig[row];
  const float* cfb = cf + (size_t)b*2048;
  float4 v  = ((const float4*)(h + (size_t)row*EE))[t];
  float4 c1 = ((const float4*)cfb)[t];
  float4 c0 = ((const float4*)(cfb + 1024))[t];
  float x0 = fmaf(v.x*rs, c1.x, c0.x);
  float x1 = fmaf(v.y*rs, c1.y, c0.y);
  float x2 = fmaf(v.z*rs, c1.z, c0.z);
  float x3 = fmaf(v.w*rs, c1.w, c0.w);
  ushort4 uh, ul;
  uh.x = f2bf(x0); ul.x = f2bf(x0 - bf2f(uh.x));
  uh.y = f2bf(x1); ul.y = f2bf(x1 - bf2f(uh.y));
  uh.z = f2bf(x2); ul.z = f2bf(x2 - bf2f(uh.z));
  uh.w = f2bf(x3); ul.w = f2bf(x3 - bf2f(uh.w));
  ((ushort4*)(xh + (size_t)row*EE))[t] = uh;
  ((ushort4*)(xl + (size_t)row*EE))[t] = ul;
}

// ------------- x2 = modulate(rmsnorm(h2)) -> bf16 ----------------
__global__ __launch_bounds__(256) void k_split2(const float* __restrict__ in,
    const float* __restrict__ rsig, const float* __restrict__ cf,
    unsigned short* __restrict__ xb) {
  int row = blockIdx.x;
  int t = threadIdx.x;
  int b = row >> 12;
  float rs = rsig[row];
  const float* cfb = cf + (size_t)b*2048;
  float4 v  = ((const float4*)(in + (size_t)row*EE))[t];
  float4 c1 = ((const float4*)cfb)[t];
  float4 c0 = ((const float4*)(cfb + 1024))[t];
  ushort4 u;
  u.x = f2bf(fmaf(v.x*rs, c1.x, c0.x));
  u.y = f2bf(fmaf(v.y*rs, c1.y, c0.y));
  u.z = f2bf(fmaf(v.z*rs, c1.z, c0.z));
  u.w = f2bf(fmaf(v.w*rs, c1.w, c0.w));
  ((ushort4*)(xb + (size_t)row*EE))[t] = u;
}

// ------- K projection: f32 SGEMM 128x128 tile, 8x8/thread (rounds 2/6/8/9
// proven, replay-deterministic). x1 on the fly. Epilogue: silu+RoPE.
__global__ __launch_bounds__(256) void k_sgemmK(
    const float* __restrict__ Ah, const float* __restrict__ W,
    const float* __restrict__ rsig, const float* __restrict__ cf,
    const float* __restrict__ cosT, const float* __restrict__ sinT,
    float* __restrict__ outq) {
  __shared__ float As[8][128];
  __shared__ float Bs[8][128];
  __shared__ float c1s[1024];
  __shared__ float c0s[1024];
  int t = threadIdx.x;
  int tx = t & 15, ty = t >> 4;
  int bm = blockIdx.x, bn = blockIdx.y;
  int srow = t >> 1, sk = (t & 1) * 4;
  int bidx = bm >> 5;
  for (int i = t; i < 1024; i += 256) {
    c1s[i] = cf[(size_t)bidx*2048 + i];
    c0s[i] = cf[(size_t)bidx*2048 + 1024 + i];
  }
  int arow = bm*128 + srow;
  float rsA = rsig[arow];
  const float* ap = Ah + (size_t)arow*EE + sk;
  const float* bp = W + (size_t)(bn*128 + srow)*EE + sk;
  float acc[8][8];
  #pragma unroll
  for (int i = 0; i < 8; i++)
    #pragma unroll
    for (int j = 0; j < 8; j++) acc[i][j] = 0.f;
  float4 pa = *(const float4*)ap;
  float4 pb = *(const float4*)bp;
  int c0 = (tx < 8) ? tx*4 : 64 + (tx - 8)*4;
  __syncthreads();
  for (int k0 = 0; k0 < EE; k0 += 8) {
    int kb = k0 + sk;
    As[sk+0][srow] = fmaf(pa.x*rsA, c1s[kb+0], c0s[kb+0]);
    As[sk+1][srow] = fmaf(pa.y*rsA, c1s[kb+1], c0s[kb+1]);
    As[sk+2][srow] = fmaf(pa.z*rsA, c1s[kb+2], c0s[kb+2]);
    As[sk+3][srow] = fmaf(pa.w*rsA, c1s[kb+3], c0s[kb+3]);
    Bs[sk+0][srow] = pb.x; Bs[sk+1][srow] = pb.y; Bs[sk+2][srow] = pb.z; Bs[sk+3][srow] = pb.w;
    __syncthreads();
    if (k0 + 8 < EE) {
      pa = *(const float4*)(ap + k0 + 8);
      pb = *(const float4*)(bp + k0 + 8);
    }
    #pragma unroll
    for (int k = 0; k < 8; k++) {
      float4 a0 = *(const float4*)&As[k][ty*8];
      float4 a1 = *(const float4*)&As[k][ty*8+4];
      float4 b0 = *(const float4*)&Bs[k][c0];
      float4 b1 = *(const float4*)&Bs[k][c0+32];
      float av[8] = {a0.x,a0.y,a0.z,a0.w,a1.x,a1.y,a1.z,a1.w};
      float bv[8]  = {b0.x,b0.y,b0.z,b0.w,b1.x,b1.y,b1.z,b1.w};
      #pragma unroll
      for (int i = 0; i < 8; i++)
        #pragma unroll
        for (int j = 0; j < 8; j++)
          acc[i][j] = fmaf(av[i], bv[j], acc[i][j]);
    }
    __syncthreads();
  }
  int head = bn*2 + (tx >= 8 ? 1 : 0);
  int d0 = (tx < 8) ? tx*4 : (tx - 8)*4;
  #pragma unroll
  for (int i = 0; i < 8; i++) {
    int m = bm*128 + ty*8 + i;
    int b = m >> 12, l = m & 4095;
    const float* cp = cosT + (size_t)l*64;
    const float* sp = sinT + (size_t)l*64;
    float4 cl  = *(const float4*)(cp + d0);
    float4 slv = *(const float4*)(sp + d0);
    float4 chv = *(const float4*)(cp + d0 + 32);
    float4 shv = *(const float4*)(sp + d0 + 32);
    float sA0 = silu_f(acc[i][0]), sA1 = silu_f(acc[i][1]), sA2 = silu_f(acc[i][2]), sA3 = silu_f(acc[i][3]);
    float sB0 = silu_f(acc[i][4]), sB1 = silu_f(acc[i][5]), sB2 = silu_f(acc[i][6]), sB3 = silu_f(acc[i][7]);
    float q00 = sA0*cl.x - sB0*slv.x;
    float q01 = sA1*cl.y - sB1*slv.y;
    float q02 = sA2*cl.z - sB2*slv.z;
    float q03 = sA3*cl.w - sB3*slv.w;
    float q10 = sB0*chv.x + sA0*shv.x;
    float q11 = sB1*chv.y + sA1*shv.y;
    float q12 = sB2*chv.z + sA2*shv.z;
    float q13 = sB3*chv.w + sA3*shv.w;
    float* op = outq + ((size_t)(b*HH + head)*LL + l)*64;
    *(float4*)(op + d0)      = make_float4(q00, q01, q02, q03);
    *(float4*)(op + d0 + 32) = make_float4(q10, q11, q12, q13);
  }
}

// ------- Q projection: 3-term split-bf16 MFMA GEMM (frozen since r6) --------
__global__ __launch_bounds__(256) void k_qk(
    const unsigned short* __restrict__ xh, const unsigned short* __restrict__ xl,
    const float* __restrict__ W,
    const float* __restrict__ cosT, const float* __restrict__ sinT,
    float* __restrict__ outq) {
  __shared__ unsigned short Ah[128*32];
  __shared__ unsigned short Al[128*32];
  __shared__ unsigned short Bh[64*40];
  __shared__ unsigned short Bl[64*40];
  int t = threadIdx.x, w = t >> 6, lane = t & 63;
  int bm = blockIdx.x, bn = blockIdx.y;
  int wm = (w & 1) * 64;
  int wn = (w >> 1) * 16;
  int r16 = lane & 15, kg = lane >> 4;
  int rin = lane >> 2, slot = lane & 3;
  int ar0 = w*32 + rin, ar1 = ar0 + 16;
  const unsigned short* ahg0 = xh + (size_t)(bm*128 + ar0)*EE + (size_t)((((ar0>>1)&3) ^ slot) * 8);
  const unsigned short* ahg1 = xh + (size_t)(bm*128 + ar1)*EE + (size_t)((((ar1>>1)&3) ^ slot) * 8);
  const unsigned short* alg0 = xl + (size_t)(bm*128 + ar0)*EE + (size_t)((((ar0>>1)&3) ^ slot) * 8);
  const unsigned short* alg1 = xl + (size_t)(bm*128 + ar1)*EE + (size_t)((((ar1>>1)&3) ^ slot) * 8);
  unsigned short* ahl0 = &Ah[(w*32 + 0) * 32];
  unsigned short* ahl1 = &Ah[(w*32 + 16) * 32];
  unsigned short* all0 = &Al[(w*32 + 0) * 32];
  unsigned short* all1 = &Al[(w*32 + 16) * 32];
  int srow = t >> 2, koff = (t & 3) * 8;
  const float* bp = W + (size_t)(bn*64 + srow)*EE + koff;
  float4 pb0 = *(const float4*)(bp + 0);
  float4 pb1 = *(const float4*)(bp + 4);
  f32x4 acc[4][2];
  #pragma unroll
  for (int i = 0; i < 4; i++) { acc[i][0] = (f32x4){0,0,0,0}; acc[i][1] = (f32x4){0,0,0,0}; }

  for (int k0 = 0; k0 < EE; k0 += 32) {
    gll16(ahg0 + k0, ahl0);
    gll16(ahg1 + k0, ahl1);
    gll16(alg0 + k0, all0);
    gll16(alg1 + k0, all1);
    {
      unsigned short h0 = f2bf(pb0.x), h1 = f2bf(pb0.y), h2 = f2bf(pb0.z), h3 = f2bf(pb0.w);
      unsigned short h4 = f2bf(pb1.x), h5 = f2bf(pb1.y), h6 = f2bf(pb1.z), h7 = f2bf(pb1.w);
      unsigned short l0 = f2bf(pb0.x - bf2f(h0)), l1 = f2bf(pb0.y - bf2f(h1));
      unsigned short l2 = f2bf(pb0.z - bf2f(h2)), l3 = f2bf(pb0.w - bf2f(h3));
      unsigned short l4 = f2bf(pb1.x - bf2f(h4)), l5 = f2bf(pb1.y - bf2f(h5));
      unsigned short l6 = f2bf(pb1.z - bf2f(h6)), l7 = f2bf(pb1.w - bf2f(h7));
      u32x4 uh, ul;
      uh[0] = ((unsigned)h1<<16)|h0; uh[1] = ((unsigned)h3<<16)|h2;
      uh[2] = ((unsigned)h5<<16)|h4; uh[3] = ((unsigned)h7<<16)|h6;
      ul[0] = ((unsigned)l1<<16)|l0; ul[1] = ((unsigned)l3<<16)|l2;
      ul[2] = ((unsigned)l5<<16)|l4; ul[3] = ((unsigned)l7<<16)|l6;
      *(u32x4*)&Bh[srow*40 + koff] = uh;
      *(u32x4*)&Bl[srow*40 + koff] = ul;
    }
    __syncthreads();
    if (k0 + 32 < EE) {
      pb0 = *(const float4*)(bp + k0 + 32);
      pb1 = *(const float4*)(bp + k0 + 36);
    }
    int brow0 = wn + r16, brow1 = wn + 32 + r16;
    s16x8 bh0 = *(const s16x8*)&Bh[brow0*40 + kg*8];
    s16x8 bl0 = *(const s16x8*)&Bl[brow0*40 + kg*8];
    s16x8 bh1 = *(const s16x8*)&Bh[brow1*40 + kg*8];
    s16x8 bl1 = *(const s16x8*)&Bl[brow1*40 + kg*8];
    #pragma unroll
    for (int i = 0; i < 4; i++) {
      int row = wm + i*16 + r16;
      int sw = ((((row>>1)&3) ^ kg) << 3);
      s16x8 ah = *(const s16x8*)&Ah[row*32 + sw];
      s16x8 al = *(const s16x8*)&Al[row*32 + sw];
      acc[i][0] = __builtin_amdgcn_mfma_f32_16x16x32_bf16(ah, bh0, acc[i][0], 0, 0, 0);
      acc[i][0] = __builtin_amdgcn_mfma_f32_16x16x32_bf16(ah, bl0, acc[i][0], 0, 0, 0);
      acc[i][0] = __builtin_amdgcn_mfma_f32_16x16x32_bf16(al, bh0, acc[i][0], 0, 0, 0);
      acc[i][1] = __builtin_amdgcn_mfma_f32_16x16x32_bf16(ah, bh1, acc[i][1], 0, 0, 0);
      acc[i][1] = __builtin_amdgcn_mfma_f32_16x16x32_bf16(ah, bl1, acc[i][1], 0, 0, 0);
      acc[i][1] = __builtin_amdgcn_mfma_f32_16x16x32_bf16(al, bh1, acc[i][1], 0, 0, 0);
    }
    __syncthreads();
  }
  int d = wn + r16;
  #pragma unroll
  for (int i = 0; i < 4; i++) {
    #pragma unroll
    for (int r = 0; r < 4; r++) {
      int mm = bm*128 + wm + i*16 + kg*4 + r;
      int b = mm >> 12, l = mm & 4095;
      const float* cp = cosT + (size_t)l*64;
      const float* sp = sinT + (size_t)l*64;
      float sl = silu_f(acc[i][0][r]);
      float sh = silu_f(acc[i][1][r]);
      float qlo = sl*cp[d]      - sh*sp[d];
      float qhi = sh*cp[d + 32] + sl*sp[d + 32];
      float* op = outq + (((size_t)(b*HH + bn))*LL + l)*64;
      op[d]      = qlo;
      op[d + 32] = qhi;
    }
  }
}

// ---- bf16 MFMA GEMM, pure global_load_lds both sides, 128x128 tile.
// EPI: 0=V(bf16 (B,H,L,64)) 1=WO(out=res+g1*acc) 2=G(Pb=silu bf16, stride 2048)
//      3=U(Pb*=acc in place)  4=D(out=res+g2*acc, res==out in-place add)
template<int EPI, int KLEN, int SA, int SB>
__global__ __launch_bounds__(256) void k_gemm2(
    const unsigned short* __restrict__ Ab,
    const unsigned short* __restrict__ Bw,
    int kbB, int bnoff,
    const float* __restrict__ res, const float* __restrict__ mod,
    unsigned short* __restrict__ outb, float* __restrict__ outf) {
  __shared__ unsigned short As[128 * 32];
  __shared__ unsigned short Bs[128 * 32];
  int t = threadIdx.x, w = t >> 6, lane = t & 63;
  int bm = blockIdx.x, bn = blockIdx.y;
  int wm = (w >> 1) * 64, wn = (w & 1) * 64;
  int rin = lane >> 2, slot = lane & 3;
  int brow0 = w*32 + rin, brow1 = brow0 + 16;
  int swz0 = (((brow0>>1)&3) ^ slot) * 8;
  int swz1 = (((brow1>>1)&3) ^ slot) * 8;
  const unsigned short* ag0 = Ab + (size_t)(bm*128 + brow0)*SA + swz0;
  const unsigned short* ag1 = Ab + (size_t)(bm*128 + brow1)*SA + swz1;
  const unsigned short* bg0 = Bw + (size_t)(bnoff + bn*128 + brow0)*SB + kbB + swz0;
  const unsigned short* bg1 = Bw + (size_t)(bnoff + bn*128 + brow1)*SB + kbB + swz1;
  unsigned short* al0 = &As[(w*32 + 0) * 32];
  unsigned short* al1 = &As[(w*32 + 16) * 32];
  unsigned short* bl0 = &Bs[(w*32 + 0) * 32];
  unsigned short* bl1 = &Bs[(w*32 + 16) * 32];
  f32x4 acc[4][4];
  #pragma unroll
  for (int i = 0; i < 4; i++)
    #pragma unroll
    for (int j = 0; j < 4; j++) acc[i][j] = (f32x4){0.f, 0.f, 0.f, 0.f};
  int r16 = lane & 15, kg = lane >> 4;
  for (int k0 = 0; k0 < KLEN; k0 += 32) {
    gll16(ag0 + k0, al0);
    gll16(ag1 + k0, al1);
    gll16(bg0 + k0, bl0);
    gll16(bg1 + k0, bl1);
    __syncthreads();
    s16x8 af[4], bfr[4];
    #pragma unroll
    for (int i = 0; i < 4; i++) {
      int row = wm + i*16 + r16;
      af[i] = *(const s16x8*)&As[row*32 + ((((row>>1)&3) ^ kg) << 3)];
    }
    #pragma unroll
    for (int j = 0; j < 4; j++) {
      int row = wn + j*16 + r16;
      bfr[j] = *(const s16x8*)&Bs[row*32 + ((((row>>1)&3) ^ kg) << 3)];
    }
    #pragma unroll
    for (int i = 0; i < 4; i++)
      #pragma unroll
      for (int j = 0; j < 4; j++)
        acc[i][j] = __builtin_amdgcn_mfma_f32_16x16x32_bf16(af[i], bfr[j], acc[i][j], 0, 0, 0);
    __syncthreads();
  }
  #pragma unroll
  for (int i = 0; i < 4; i++) {
    #pragma unroll
    for (int j = 0; j < 4; j++) {
      int nn = bn*128 + wn + j*16 + r16;
      #pragma unroll
      for (int r = 0; r < 4; r++) {
        int mm = bm*128 + wm + i*16 + kg*4 + r;
        float v = acc[i][j][r];
        if constexpr (EPI == 0) {
          int b = mm >> 12, l = mm & 4095, hh = nn >> 6, dd = nn & 63;
          outb[(((size_t)(b*HH + hh))*LL + l)*64 + dd] = f2bf(v);
        } else if constexpr (EPI == 1) {
          int b = mm >> 12;
          size_t o = (size_t)mm*EE + nn;
          outf[o] = res[o] + mod[(size_t)b*6*EE + 2*EE + nn] * v;
        } else if constexpr (EPI == 2) {
          outb[(size_t)mm*2048 + nn] = f2bf(silu_f(v));
        } else if constexpr (EPI == 3) {
          size_t o = (size_t)mm*2048 + nn;
          outb[o] = f2bf(bf2f(outb[o]) * v);
        } else {
          int b = mm >> 12;
          size_t o = (size_t)mm*EE + nn;
          outf[o] = res[o] + mod[(size_t)b*6*EE + 5*EE + nn] * v;
        }
      }
    }
  }
}

// ---- kv partials over 512-l chunks ----
__global__ __launch_bounds__(256) void k_kvpart(const float* __restrict__ kr,
    const unsigned short* __restrict__ vtb, float* __restrict__ kvp) {
  int bi = blockIdx.x;
  int bh = bi >> 3, ch = bi & 7;
  const float* kp = kr + ((size_t)bh*LL + ch*512)*64;
  const unsigned short* vp = vtb + ((size_t)bh*LL + ch*512)*64;
  __shared__ float k8[8][64];
  __shared__ float v8[8][64];
  __shared__ float sw8[8], cw8[8];
  int t = threadIdx.x;
  int d = t >> 2, mq = (t & 3) * 16;
  float accS[16], accC[16];
  #pragma unroll
  for (int q = 0; q < 16; q++) { accS[q] = 0.f; accC[q] = 0.f; }
  float ksS = 0.f, ksC = 0.f;
  for (int l0 = 0; l0 < 512; l0 += 8) {
    __syncthreads();
    #pragma unroll
    for (int rep = 0; rep < 2; rep++) {
      int idx = rep*256 + t;
      k8[idx>>6][idx&63] = kp[(size_t)(l0 + (idx>>6))*64 + (idx&63)];
      v8[idx>>6][idx&63] = bf2f(vp[(size_t)(l0 + (idx>>6))*64 + (idx&63)]);
    }
    if (t < 8) {
      int gl = ch*512 + l0 + t;
      float idxv = 1.5707964f * (float)(gl + 1) * (1.0f/4096.0f);
      sw8[t] = sinf(idxv);
      cw8[t] = cosf(idxv);
    }
    __syncthreads();
    #pragma unroll
    for (int l = 0; l < 8; l++) {
      float kd = k8[l][d];
      float s = kd * sw8[l];
      float c = kd * cw8[l];
      ksS += s; ksC += c;
      const float4* vv = (const float4*)&v8[l][mq];
      #pragma unroll
      for (int q = 0; q < 4; q++) {
        float4 x = vv[q];
        accS[4*q+0] = fmaf(s, x.x, accS[4*q+0]);
        accS[4*q+1] = fmaf(s, x.y, accS[4*q+1]);
        accS[4*q+2] = fmaf(s, x.z, accS[4*q+2]);
        accS[4*q+3] = fmaf(s, x.w, accS[4*q+3]);
        accC[4*q+0] = fmaf(c, x.x, accC[4*q+0]);
        accC[4*q+1] = fmaf(c, x.y, accC[4*q+1]);
        accC[4*q+2] = fmaf(c, x.z, accC[4*q+2]);
        accC[4*q+3] = fmaf(c, x.w, accC[4*q+3]);
      }
    }
  }
  float* op = kvp + (size_t)bi * 8320;
  #pragma unroll
  for (int q = 0; q < 16; q++) {
    op[d*64 + mq + q]        = accS[q];
    op[4096 + d*64 + mq + q] = accC[q];
  }
  if (mq == 0) { op[8192 + d] = ksS; op[8256 + d] = ksC; }
}

// kvred + zf_cnt zeroing (cnt lives in mod-region slack, validated in r12)
__global__ __launch_bounds__(256) void k_kvred(const float* __restrict__ kvp,
    float* __restrict__ kvb, int* __restrict__ cnt) {
  int bh = blockIdx.x;
  if (bh == 0 && threadIdx.x == 0) *cnt = 0;
  for (int i = threadIdx.x; i < 8320; i += 256) {
    float s = 0.f;
    #pragma unroll
    for (int c = 0; c < 8; c++) s += kvp[((size_t)bh*8 + c)*8320 + i];
    kvb[(size_t)bh*8320 + i] = s;
  }
}

// --- z = 1/max(sw*(q.ksS)+cw*(q.ksC), eps); flag |denom|<TAU for exact redo ---
__global__ __launch_bounds__(256) void k_z(const float* __restrict__ qr,
    const float* __restrict__ kvb, float* __restrict__ zb,
    int* __restrict__ list, int* __restrict__ cnt) {
  int bh = blockIdx.x >> 6, lc = blockIdx.x & 63;
  __shared__ float ksS_s[64], ksC_s[64];
  int t = threadIdx.x;
  if (t < 64) ksS_s[t] = kvb[(size_t)bh*8320 + 8192 + t];
  else if (t < 128) ksC_s[t-64] = kvb[(size_t)bh*8320 + 8256 + (t-64)];
  __syncthreads();
  int l = lc*64 + (t >> 2), part = t & 3;
  const float4* qp = (const float4*)(qr + ((size_t)bh*LL + l)*64 + part*16);
  float A = 0.f, Bv = 0.f;
  #pragma unroll
  for (int q = 0; q < 4; q++) {
    float4 x = qp[q];
    int kb = part*16 + 4*q;
    A  += x.x*ksS_s[kb] + x.y*ksS_s[kb+1] + x.z*ksS_s[kb+2] + x.w*ksS_s[kb+3];
    Bv += x.x*ksC_s[kb] + x.y*ksC_s[kb+1] + x.z*ksC_s[kb+2] + x.w*ksC_s[kb+3];
  }
  A  += __shfl_xor(A, 1, 64);  A  += __shfl_xor(A, 2, 64);
  Bv += __shfl_xor(Bv, 1, 64); Bv += __shfl_xor(Bv, 2, 64);
  if (part == 0) {
    float idxv = 1.5707964f * (float)(l + 1) * (1.0f/4096.0f);
    float denom = sinf(idxv)*A + cosf(idxv)*Bv;
    int gid = bh*LL + l;
    zb[gid] = 1.0f / fmaxf(denom, 1e-6f);
    if (fabsf(denom) < 0.05f) {
      int idx = atomicAdd(cnt, 1);
      if (idx < 8000) list[idx] = gid;
    }
  }
}

// --- exact z recompute for flagged rows: f32 x from h, f64 GEMV over Wq ---
__global__ __launch_bounds__(256) void k_zfix(const float* __restrict__ h,
    const float* __restrict__ rsig, const float* __restrict__ cf,
    const float* __restrict__ Wq,
    const float* __restrict__ cosT, const float* __restrict__ sinT,
    const float* __restrict__ kvb, const int* __restrict__ list,
    const int* __restrict__ cnt, float* __restrict__ zb) {
  __shared__ float xs[1024];
  __shared__ double qd[64];
  __shared__ double sq[64];
  int n = *cnt;
  if (n > 8000) n = 8000;
  int t = threadIdx.x;
  for (int i = blockIdx.x; i < n; i += gridDim.x) {
    int gid = list[i];
    int bh = gid >> 12, l = gid & 4095;
    int b = bh >> 4, hh = bh & 15;
    int row = b*4096 + l;
    float rs = rsig[row];
    const float* cfb = cf + (size_t)b*2048;
    for (int k = t; k < 1024; k += 256)
      xs[k] = fmaf(h[(size_t)row*1024 + k]*rs, cfb[k], cfb[1024 + k]);
    __syncthreads();
    int j = t >> 2, s = t & 3;
    const float* wrow = Wq + (size_t)(hh*64 + j)*1024 + s*256;
    double acc = 0.0;
    for (int k = 0; k < 256; k++)
      acc += (double)wrow[k] * (double)xs[s*256 + k];
    acc += __shfl_xor(acc, 1, 64);
    acc += __shfl_xor(acc, 2, 64);
    if (s == 0) qd[j] = acc;
    __syncthreads();
    if (t < 64) {
      double qv = qd[t];
      sq[t] = qv / (1.0 + exp(-qv));
    }
    __syncthreads();
    if (t == 0) {
      const float* cp = cosT + (size_t)l*64;
      const float* sp = sinT + (size_t)l*64;
      const float* ksS = kvb + (size_t)bh*8320 + 8192;
      const float* ksC = kvb + (size_t)bh*8320 + 8256;
      double dS = 0.0, dC = 0.0;
      for (int d = 0; d < 64; d++) {
        double rot = (d < 32) ? -sq[d + 32] : sq[d - 32];
        double qe = sq[d]*(double)cp[d] + rot*(double)sp[d];
        dS += qe * (double)ksS[d];
        dC += qe * (double)ksC[d];
      }
      double idxv = 1.5707963267948966 * (double)(l + 1) / 4096.0;
      float denom = (float)(sin(idxv)*dS + cos(idxv)*dC);
      zb[gid] = 1.0f / fmaxf(denom, 1e-6f);
    }
    __syncthreads();
  }
}

// --- attn numerator + z ---
__global__ __launch_bounds__(256) void k_attn(const float* __restrict__ qr,
    const float* __restrict__ kvb, const float* __restrict__ zb,
    unsigned short* __restrict__ attnb) {
  int bh = blockIdx.x >> 4, lc = blockIdx.x & 15;
  int t = threadIdx.x, w = t >> 6, lane = t & 63;
  const float* kvp_ = kvb + (size_t)bh*8320;
  float kvS[64], kvC[64];
  #pragma unroll
  for (int d = 0; d < 64; d++) kvS[d] = kvp_[d*64 + lane];
  #pragma unroll
  for (int d = 0; d < 64; d++) kvC[d] = kvp_[4096 + d*64 + lane];
  int b = bh >> 4, hh = bh & 15;
  int lbase = lc*256 + w*64;
  for (int li = 0; li < 64; li++) {
    int l = lbase + li;
    const float* qp = qr + ((size_t)bh*LL + l)*64;
    float qv = qp[lane];
    float z = zb[(size_t)bh*LL + l];
    float a0 = 0.f, a1 = 0.f, a2 = 0.f, a3 = 0.f;
    float b0 = 0.f, b1 = 0.f, b2 = 0.f, b3 = 0.f;
    #pragma unroll
    for (int d = 0; d < 64; d += 4) {
      float q0 = __uint_as_float(__builtin_amdgcn_readlane(__float_as_uint(qv), d+0));
      float q1 = __uint_as_float(__builtin_amdgcn_readlane(__float_as_uint(qv), d+1));
      float q2 = __uint_as_float(__builtin_amdgcn_readlane(__float_as_uint(qv), d+2));
      float q3 = __uint_as_float(__builtin_amdgcn_readlane(__float_as_uint(qv), d+3));
      a0 = fmaf(q0, kvS[d+0], a0);
      a1 = fmaf(q1, kvS[d+1], a1);
      a2 = fmaf(q2, kvS[d+2], a2);
      a3 = fmaf(q3, kvS[d+3], a3);
      b0 = fmaf(q0, kvC[d+0], b0);
      b1 = fmaf(q1, kvC[d+1], b1);
      b2 = fmaf(q2, kvC[d+2], b2);
      b3 = fmaf(q3, kvC[d+3], b3);
    }
    float A = (a0 + a1) + (a2 + a3);
    float Bv = (b0 + b1) + (b2 + b3);
    float idxv = 1.5707964f * (float)(l + 1) * (1.0f/4096.0f);
    float num = sinf(idxv)*A + cosf(idxv)*Bv;
    attnb[(((size_t)b*LL + l)*HH + hh)*64 + lane] = f2bf(num * z);
  }
}

extern "C" void kernel_launch(void* const* d_in, const int* in_sizes, int n_in,
                              void* d_out, int out_size, void* d_ws, size_t ws_size,
                              hipStream_t stream) {
  const float* h    = (const float*)d_in[0];
  const float* c    = (const float*)d_in[1];
  const float* cosT = (const float*)d_in[2];
  const float* sinT = (const float*)d_in[3];
  const float* Wq   = (const float*)d_in[4];
  const float* Wk   = (const float*)d_in[5];
  const float* Wv   = (const float*)d_in[6];
  const float* Wo   = (const float*)d_in[7];
  const float* Wg   = (const float*)d_in[8];
  const float* Wu   = (const float*)d_in[9];
  const float* Wd   = (const float*)d_in[10];
  const float* w1   = (const float*)d_in[11];
  const float* w2   = (const float*)d_in[12];
  const float* Wada = (const float*)d_in[13];
  const float* bada = (const float*)d_in[14];
  float* out = (float*)d_out;

  // ---- workspace layout (total 167,084,032 B, proven rounds 2..13) ----
  constexpr size_t BIG_SZ   = (size_t)MM * II * 2;          // 134,217,728
  constexpr size_t WS_NEEDED = BIG_SZ + 131072 + 32768*2 + 65536*2
      + 1048576 + 2129920 + 2097152*2 + 8388608*3;
  if (ws_size < WS_NEEDED) return;

  char* p = (char*)d_ws;
  char* big = p;                               p += BIG_SZ;
  float* mod = (float*)p;                      p += 131072;
  float* cf1 = (float*)p;                      p += 32768;
  float* cf2 = (float*)p;                      p += 32768;
  float* rsig1 = (float*)p;                    p += 65536;
  float* rsig2 = (float*)p;                    p += 65536;
  float* zb  = (float*)p;                      p += 1048576;
  float* kvb = (float*)p;                      p += 2129920;
  unsigned short* Wvb = (unsigned short*)p;    p += 2097152;
  unsigned short* Wob = (unsigned short*)p;    p += 2097152;
  unsigned short* Wgb = (unsigned short*)p;    p += 8388608;
  unsigned short* Wub = (unsigned short*)p;    p += 8388608;
  unsigned short* Wdb = (unsigned short*)p;    p += 8388608;
  // zf_cnt/zf_list in mod-region slack (mod uses 98304 of 131072 B; r12-validated)
  int* zf_cnt  = (int*)((char*)mod + 98304);
  int* zf_list = zf_cnt + 64;
  // time-shared arena inside BIG (128 MiB), round-9-proven lifetimes:
  //   xh,xl   : [split1 .. k_qk]        (0-64M)
  //   vtb     : [V .. kvpart]           (64-96M)
  //   kvp     : [kvpart .. kvred]       (96-112.3M)
  //   qr      : [k_qk .. k_attn]        (64-128M)
  //   attnb   : [k_attn .. WO]          (0-64M head)
  //   x2b     : [split2 .. G/U]         (0-32M)
  //   Pb(half): [G .. D]                (32-96M)
  unsigned short* xh   = (unsigned short*)big;
  unsigned short* xl   = (unsigned short*)(big + 33554432);
  unsigned short* vtb  = (unsigned short*)(big + 67108864);
  float* kvp           = (float*)(big + 100663296);
  float* qr            = (float*)(big + 67108864);
  unsigned short* attnb= (unsigned short*)big;
  unsigned short* x2b  = (unsigned short*)big;
  unsigned short* Pb   = (unsigned short*)(big + 33554432);
  float* kr            = (float*)d_out;

  k_mod<<<dim3(24, BB), 256, 0, stream>>>(c, Wada, bada, mod);
  k_coef<<<dim3(4, BB), 256, 0, stream>>>(mod, w1, w2, cf1, cf2);
  k_rsig<<<MM, 256, 0, stream>>>(h, rsig1);
  k_f2b<<<1024, 256, 0, stream>>>(Wv, Wvb, EE*EE/4);
  k_f2b<<<1024, 256, 0, stream>>>(Wo, Wob, EE*EE/4);
  k_f2b<<<4096, 256, 0, stream>>>(Wg, Wgb, II*EE/4);
  k_f2b<<<4096, 256, 0, stream>>>(Wu, Wub, II*EE/4);
  k_f2b<<<4096, 256, 0, stream>>>(Wd, Wdb, EE*II/4);
  k_split1<<<MM, 256, 0, stream>>>(h, rsig1, cf1, xh, xl);

  // K projection (f32 SGEMM 128x128, proven) -> kr (in d_out); V; kv reduction
  k_sgemmK<<<dim3(128, 8), 256, 0, stream>>>(h, Wk, rsig1, cf1, cosT, sinT, kr);
  k_gemm2<0, EE, EE, EE><<<dim3(128, 8), 256, 0, stream>>>(
      xh, Wvb, 0, 0, nullptr, nullptr, vtb, nullptr);
  k_kvpart<<<BB*HH*8, 256, 0, stream>>>(kr, vtb, kvp);
  k_kvred<<<BB*HH, 256, 0, stream>>>(kvp, kvb, zf_cnt);

  // Q projection (split-bf16) -> qr; z with flagging; exact fixup; attn
  k_qk<<<dim3(128, 16), 256, 0, stream>>>(xh, xl, Wq, cosT, sinT, qr);
  k_z<<<BB*HH*(LL/64), 256, 0, stream>>>(qr, kvb, zb, zf_list, zf_cnt);
  k_zfix<<<120, 256, 0, stream>>>(h, rsig1, cf1, Wq, cosT, sinT, kvb,
                                  zf_list, zf_cnt, zb);
  k_attn<<<BB*HH*(LL/256), 256, 0, stream>>>(qr, kvb, zb, attnb);

  // WO projection + residual -> out
  k_gemm2<1, EE, EE, EE><<<dim3(128, 8), 256, 0, stream>>>(
      attnb, Wob, 0, 0, h, mod, nullptr, out);

  // MLP: x2 precomputed bf16 once; separate G/U/D per half (r9-proven).
  k_rsig<<<MM, 256, 0, stream>>>(out, rsig2);
  k_split2<<<MM, 256, 0, stream>>>(out, rsig2, cf2, x2b);
  for (int half = 0; half < 2; half++) {
    k_gemm2<2, EE, EE, EE><<<dim3(128, 16), 256, 0, stream>>>(
        x2b, Wgb, 0, half*2048, nullptr, nullptr, Pb, nullptr);
    k_gemm2<3, EE, EE, EE><<<dim3(128, 16), 256, 0, stream>>>(
        x2b, Wub, 0, half*2048, nullptr, nullptr, Pb, nullptr);
    k_gemm2<4, 2048, 2048, II><<<dim3(128, 8), 256, 0, stream>>>(
        Pb, Wdb, half*2048, 0, out, mod, nullptr, out);
  }
}